// Round 4
// baseline (168.846 us; speedup 1.0000x reference)
//
#include <hip/hip_runtime.h>
#include <hip/hip_bf16.h>

typedef __bf16 bf16x8 __attribute__((ext_vector_type(8)));
typedef float f32x4 __attribute__((ext_vector_type(4)));
typedef float f32x16 __attribute__((ext_vector_type(16)));
typedef unsigned short u16;
typedef unsigned int u32;
typedef u16 u16x8 __attribute__((ext_vector_type(8)));
typedef u32 u32x4 __attribute__((ext_vector_type(4)));

#define SM_SCALE 0.1803368801111244f  // (1/8) * log2(e)

// f32 -> bf16 round-to-nearest-even
__device__ inline u16 tobf(float f) {
  u32 u = __builtin_bit_cast(u32, f);
  u32 r = (u + 0x7fffu + ((u >> 16) & 1u)) >> 16;
  return (u16)r;
}

__device__ inline void gload_lds16(const void* g, void* lds) {
  __builtin_amdgcn_global_load_lds(
      (const __attribute__((address_space(1))) u32*)g,
      (__attribute__((address_space(3))) u32*)lds, 16, 0, 0);
}

// ---------------- convert x (f32 -> bf16), 8 elems/thread ----------------
__global__ void convert_f32_bf16(const float* __restrict__ in,
                                 u16* __restrict__ out, int n8) {
  int i = blockIdx.x * blockDim.x + threadIdx.x;
  int stride = gridDim.x * blockDim.x;
  for (; i < n8; i += stride) {
    const float4* p = (const float4*)in + (size_t)i * 2;
    float4 a = p[0], b = p[1];
    u16x8 v;
    v[0] = tobf(a.x); v[1] = tobf(a.y); v[2] = tobf(a.z); v[3] = tobf(a.w);
    v[4] = tobf(b.x); v[5] = tobf(b.y); v[6] = tobf(b.z); v[7] = tobf(b.w);
    *(u16x8*)(out + (size_t)i * 8) = v;
  }
}

// ---------------- transpose + cast weights: out[n][k] = in[k][n] ----------
__global__ void transpose_w(const float* __restrict__ in,
                            u16* __restrict__ out, int K, int N) {
  __shared__ float tile[32][33];
  int nbx = N >> 5;
  int bx = blockIdx.x % nbx, by = blockIdx.x / nbx;
  int k0 = by << 5, n0 = bx << 5;
  int tx = threadIdx.x & 31, ty = threadIdx.x >> 5;
#pragma unroll
  for (int j = 0; j < 4; ++j) {
    int row = ty + j * 8;
    tile[row][tx] = in[(size_t)(k0 + row) * N + n0 + tx];
  }
  __syncthreads();
#pragma unroll
  for (int j = 0; j < 4; ++j) {
    int row = ty + j * 8;
    out[(size_t)(n0 + row) * K + k0 + tx] = tobf(tile[tx][row]);
  }
}

// ---------------- GEMM: C[M,N] = A[M,K] * Bt[N,K]^T  (bf16 in, f32 acc) ---
template <int EPI>
__global__ __launch_bounds__(256) void gemm_bt(
    const u16* __restrict__ A, const u16* __restrict__ Bt,
    const float* __restrict__ bias,
    u16* __restrict__ o0, u16* __restrict__ o1, u16* __restrict__ o2,
    float* __restrict__ fo, int M, int N, int K) {
  __shared__ __align__(16) u16 As[128 * 64];
  __shared__ __align__(16) u16 Bs[128 * 64];
  const int tid = threadIdx.x;
  const int lane = tid & 63;
  const int wave = tid >> 6;
  const int nbn = N >> 7;
  const int bm = (int)blockIdx.x / nbn, bn = (int)blockIdx.x % nbn;
  const int m0 = bm << 7, n0 = bn << 7;
  const int wr = wave >> 1, wc = wave & 1;
  const int r15 = lane & 15, g = lane >> 4;

  f32x4 acc[4][4] = {};

  const int nkt = K >> 6;
  for (int kt = 0; kt < nkt; ++kt) {
#pragma unroll
    for (int j = 0; j < 4; ++j) {
      int c = j * 4 + wave;
      int byte0 = c * 1024 + lane * 16;
      int row = byte0 >> 7;
      int colb = (byte0 & 127) ^ ((row & 7) << 4);
      gload_lds16(A + (size_t)(m0 + row) * K + kt * 64 + (colb >> 1),
                  (char*)As + c * 1024);
      gload_lds16(Bt + (size_t)(n0 + row) * K + kt * 64 + (colb >> 1),
                  (char*)Bs + c * 1024);
    }
    __syncthreads();
#pragma unroll
    for (int kk = 0; kk < 64; kk += 32) {
      bf16x8 af[4], bf[4];
#pragma unroll
      for (int i = 0; i < 4; ++i) {
        int rowA = wr * 64 + i * 16 + r15;
        int ca = (kk * 2 + 16 * g) ^ ((rowA & 7) << 4);
        af[i] = *(const bf16x8*)((const char*)As + rowA * 128 + ca);
        int rowB = wc * 64 + i * 16 + r15;
        int cb = (kk * 2 + 16 * g) ^ ((rowB & 7) << 4);
        bf[i] = *(const bf16x8*)((const char*)Bs + rowB * 128 + cb);
      }
#pragma unroll
      for (int i = 0; i < 4; ++i)
#pragma unroll
        for (int j2 = 0; j2 < 4; ++j2)
          acc[i][j2] = __builtin_amdgcn_mfma_f32_16x16x32_bf16(
              af[i], bf[j2], acc[i][j2], 0, 0, 0);
    }
    __syncthreads();
  }
#pragma unroll
  for (int j2 = 0; j2 < 4; ++j2) {
    int n = n0 + wc * 64 + j2 * 16 + r15;
    float bv = bias[n];
#pragma unroll
    for (int i = 0; i < 4; ++i) {
      int mbase = m0 + wr * 64 + i * 16 + g * 4;
#pragma unroll
      for (int rr = 0; rr < 4; ++rr) {
        float val = acc[i][j2][rr] + bv;
        int m = mbase + rr;
        if (EPI == 0) {
          u16 hv = tobf(val);
          int b = m >> 11, t = m & 2047;
          int sec = n >> 10, nn = n & 1023;
          int h = nn >> 6, d = nn & 63;
          if (sec == 0)
            o0[((size_t)((b * 16 + h) * 2048 + t)) * 64 + d] = hv;
          else if (sec == 1)
            o1[((size_t)((b * 16 + h) * 2048 + t)) * 64 + d] = hv;
          else
            o2[((size_t)((b * 16 + h) * 64 + d)) * 2048 + t] = hv;
        } else {
          fo[(size_t)m * N + n] = val;
        }
      }
    }
  }
}

// ---------------- causal flash attention v4 (swapped QK^T, 32x32) ---------
// 256 thr / 4 waves; wave owns 32 q-rows (128 q/block); KV tiles 64; dbuf
// staging. Swapped mfma(K,Q): lane owns ONE q row (q = lane&31); softmax
// state (m, l) is per-lane scalar; P redistributed in-register via
// cvt_pk_bf16 + permlane32_swap; PV as O^T = mfma(V^T, P).
// Grid 512: pairs (bx, bx+256) have complementary work (sum = const).
__global__ __launch_bounds__(256) void attn_kernel(
    const u16* __restrict__ qb, const u16* __restrict__ kb,
    const u16* __restrict__ vt, u16* __restrict__ yb) {
  __shared__ __align__(16) u16 Ks[2][64 * 64];
  __shared__ __align__(16) u16 Vs[2][64 * 64];
  const int tid = threadIdx.x;
  const int lane = tid & 63;
  const int w = tid >> 6;                       // 0..3
  const int q31 = lane & 31, hi = lane >> 5;
  const int bx = blockIdx.x;
  const int c = (bx < 256) ? (15 - (bx >> 5)) : ((bx - 256) >> 5);
  const int bh = bx & 31;

  const int q0 = c * 128 + w * 32;              // wave's first q row
  const int qmax = q0 + 31;
  const int nt = 2 * c + 2;                     // KV tiles in block

  // staging: identical pattern to v3 (linear LDS dest, pre-swizzled source)
  const int srow = tid >> 3;                    // 0..31
  const int scolb = ((tid & 7) * 16) ^ ((srow & 7) << 4);
  const u16* ksrc = kb + ((size_t)bh * 2048 + srow) * 64 + (scolb >> 1);
  const u16* vsrc = vt + ((size_t)bh * 64 + srow) * 2048 + (scolb >> 1);

#define STAGE(buf, kt)                                                     \
  do {                                                                     \
    gload_lds16(ksrc + (size_t)(kt) * 4096, (char*)Ks[buf] + w * 1024);    \
    gload_lds16(ksrc + (size_t)(kt) * 4096 + 32 * 64,                      \
                (char*)Ks[buf] + 4096 + w * 1024);                         \
    gload_lds16(vsrc + (kt) * 64, (char*)Vs[buf] + w * 1024);              \
    gload_lds16(vsrc + (kt) * 64 + 32 * 2048,                              \
                (char*)Vs[buf] + 4096 + w * 1024);                         \
  } while (0)

  // Q fragments: lane holds Q[q0+q31][d = ks*16 + 8*hi .. +8), ks=0..3
  const u16* qrow = qb + ((size_t)bh * 2048 + q0 + q31) * 64;
  bf16x8 aq[4];
#pragma unroll
  for (int ks = 0; ks < 4; ++ks)
    aq[ks] = *(const bf16x8*)(qrow + ks * 16 + 8 * hi);

  f32x16 o0 = {}, o1 = {};      // O^T: lane q=q31; d=(r&3)+8(r>>2)+4hi (+32)
  float m = -INFINITY, l = 0.f; // per-lane (per-q-row) softmax state
  const int qg = q0 + q31;

  STAGE(0, 0);
  __syncthreads();
  int cur = 0;
  for (int kt = 0; kt < nt; ++kt) {
    if (kt + 1 < nt) STAGE(cur ^ 1, kt + 1);
    if (kt * 64 <= qmax) {
      const char* Kc = (const char*)Ks[cur];
      const char* Vc = (const char*)Vs[cur];
      const int swz = (q31 & 7) << 4;  // same for rows q31 and q31+32

      // S^T = K Q^T : s0 = kv[0..32), s1 = kv[32..64); col q = lane&31
      f32x16 s0 = {}, s1 = {};
      __builtin_amdgcn_s_setprio(1);
#pragma unroll
      for (int ks = 0; ks < 4; ++ks) {
        int cb = (32 * ks + 16 * hi) ^ swz;
        bf16x8 k0 = *(const bf16x8*)(Kc + q31 * 128 + cb);
        s0 = __builtin_amdgcn_mfma_f32_32x32x16_bf16(k0, aq[ks], s0, 0, 0, 0);
        bf16x8 k1 = *(const bf16x8*)(Kc + (32 + q31) * 128 + cb);
        s1 = __builtin_amdgcn_mfma_f32_32x32x16_bf16(k1, aq[ks], s1, 0, 0, 0);
      }
      __builtin_amdgcn_s_setprio(0);

      // scale + causal mask (log2 domain); in-lane max over 32 values
      const bool anymask = (kt * 64 + 63 > q0);
      float mt = -INFINITY;
#pragma unroll
      for (int r = 0; r < 16; ++r) {
        float sv = s0[r] * SM_SCALE;
        float sw = s1[r] * SM_SCALE;
        if (anymask) {
          int kvg = kt * 64 + (r & 3) + 8 * (r >> 2) + 4 * hi;
          if (kvg > qg) sv = -INFINITY;
          if (kvg + 32 > qg) sw = -INFINITY;
        }
        s0[r] = sv;
        s1[r] = sw;
        mt = fmaxf(mt, fmaxf(sv, sw));
      }
      mt = fmaxf(mt, __shfl_xor(mt, 32, 64));  // combine kv-halves (same q)

      // defer-max: rescale only when row max grew by > 8 (log2 domain)
      if (__any(mt > m + 8.f)) {
        float mnew = fmaxf(m, mt);
        float alpha = exp2f(m - mnew);
        m = mnew;
        l *= alpha;
#pragma unroll
        for (int r = 0; r < 16; ++r) {
          o0[r] *= alpha;
          o1[r] *= alpha;
        }
      }
      // exp (in place) + per-lane partial sum
#pragma unroll
      for (int r = 0; r < 16; ++r) {
        float p0 = exp2f(s0[r] - m);
        float p1 = exp2f(s1[r] - m);
        l += p0 + p1;
        s0[r] = p0;
        s1[r] = p1;
      }
      // pack to bf16 pairs: W[i]   = kv(4hi+2i..+1) of tile half 0
      //                     W[8+i] = same for half 1
      u32 W[16];
#pragma unroll
      for (int i = 0; i < 8; ++i) {
        asm("v_cvt_pk_bf16_f32 %0, %1, %2"
            : "=v"(W[i]) : "v"(s0[2 * i]), "v"(s0[2 * i + 1]));
        asm("v_cvt_pk_bf16_f32 %0, %1, %2"
            : "=v"(W[8 + i]) : "v"(s1[2 * i]), "v"(s1[2 * i + 1]));
      }
      // redistribute halves: after swap, W[4k..4k+3] = contiguous kv
      // [16k + 8hi, +8) for this lane = PV A-frag words
#pragma unroll
      for (int b4 = 0; b4 < 16; b4 += 4) {
        asm("v_permlane32_swap_b32 %0, %1" : "+v"(W[b4]), "+v"(W[b4 + 2]));
        asm("v_permlane32_swap_b32 %0, %1" : "+v"(W[b4 + 1]), "+v"(W[b4 + 3]));
      }
      // PV: O^T += V^T * P^T  (lane: row d, col q)
      __builtin_amdgcn_s_setprio(1);
#pragma unroll
      for (int ks = 0; ks < 4; ++ks) {
        u32x4 pwv = {W[4 * ks], W[4 * ks + 1], W[4 * ks + 2], W[4 * ks + 3]};
        bf16x8 pf = __builtin_bit_cast(bf16x8, pwv);
        int cb = (32 * ks + 16 * hi) ^ swz;
        bf16x8 v0 = *(const bf16x8*)(Vc + q31 * 128 + cb);
        o0 = __builtin_amdgcn_mfma_f32_32x32x16_bf16(v0, pf, o0, 0, 0, 0);
        bf16x8 v1 = *(const bf16x8*)(Vc + (32 + q31) * 128 + cb);
        o1 = __builtin_amdgcn_mfma_f32_32x32x16_bf16(v1, pf, o1, 0, 0, 0);
      }
      __builtin_amdgcn_s_setprio(0);
    }
    __syncthreads();
    cur ^= 1;
  }
#undef STAGE

  // final: combine partner's partial sum (other kv half, same q)
  l += __shfl_xor(l, 32, 64);
  float inv = 1.0f / l;

  // epilogue: lane writes row t=q0+q31, d = (r&3)+8(r>>2)+4hi (+32 for o1)
  int b = bh >> 4, h = bh & 15;
  u32* dst = (u32*)(yb + ((size_t)b * 2048 + q0 + q31) * 1024 + h * 64);
#pragma unroll
  for (int r = 0; r < 16; r += 2) {
    int d = (r & 3) + 8 * (r >> 2) + 4 * hi;
    u32 w0 = (u32)tobf(o0[r] * inv) | ((u32)tobf(o0[r + 1] * inv) << 16);
    dst[d >> 1] = w0;
    u32 w1 = (u32)tobf(o1[r] * inv) | ((u32)tobf(o1[r + 1] * inv) << 16);
    dst[(d + 32) >> 1] = w1;
  }
}

extern "C" void kernel_launch(void* const* d_in, const int* in_sizes, int n_in,
                              void* d_out, int out_size, void* d_ws,
                              size_t ws_size, hipStream_t stream) {
  const float* x = (const float*)d_in[0];
  const float* w_attn = (const float*)d_in[1];
  const float* b_attn = (const float*)d_in[2];
  const float* w_proj = (const float*)d_in[3];
  const float* b_proj = (const float*)d_in[4];
  float* out = (float*)d_out;
  char* ws = (char*)d_ws;

  u16* xb = (u16*)ws;                          // 8 MB  [4096][1024]
  u16* wat = (u16*)(ws + (8ull << 20));        // 6 MB  [3072][1024]
  u16* wpt = (u16*)(ws + (14ull << 20));       // 2 MB  [1024][1024]
  u16* qbuf = (u16*)(ws + (16ull << 20));      // 8 MB  [B,H,T,D]
  u16* kbuf = (u16*)(ws + (24ull << 20));      // 8 MB  [B,H,T,D]
  u16* vtb = (u16*)(ws + (32ull << 20));       // 8 MB  [B,H,D,T]
  u16* yb = (u16*)(ws + (40ull << 20));        // 8 MB  [4096][1024]

  convert_f32_bf16<<<2048, 256, 0, stream>>>(x, xb, (4096 * 1024) / 8);
  transpose_w<<<3072, 256, 0, stream>>>(w_attn, wat, 1024, 3072);
  transpose_w<<<1024, 256, 0, stream>>>(w_proj, wpt, 1024, 1024);
  gemm_bt<0><<<32 * 24, 256, 0, stream>>>(xb, wat, b_attn, qbuf, kbuf, vtb,
                                          nullptr, 4096, 3072, 1024);
  attn_kernel<<<512, 256, 0, stream>>>(qbuf, kbuf, vtb, yb);
  gemm_bt<1><<<32 * 8, 256, 0, stream>>>(yb, wpt, b_proj, nullptr, nullptr,
                                         nullptr, out, 4096, 1024, 1024);
}

// Round 5
// 160.272 us; speedup vs baseline: 1.0535x; 1.0535x over previous
//
#include <hip/hip_runtime.h>
#include <hip/hip_bf16.h>

typedef __bf16 bf16x8 __attribute__((ext_vector_type(8)));
typedef float f32x4 __attribute__((ext_vector_type(4)));
typedef float f32x16 __attribute__((ext_vector_type(16)));
typedef unsigned short u16;
typedef unsigned int u32;
typedef u16 u16x8 __attribute__((ext_vector_type(8)));
typedef u32 u32x4 __attribute__((ext_vector_type(4)));

#define SM_SCALE 0.1803368801111244f  // (1/8) * log2(e)

// f32 -> bf16 round-to-nearest-even
__device__ inline u16 tobf(float f) {
  u32 u = __builtin_bit_cast(u32, f);
  u32 r = (u + 0x7fffu + ((u >> 16) & 1u)) >> 16;
  return (u16)r;
}

__device__ inline float frombf(u16 h) {
  return __builtin_bit_cast(float, (u32)h << 16);
}

__device__ inline void gload_lds16(const void* g, void* lds) {
  __builtin_amdgcn_global_load_lds(
      (const __attribute__((address_space(1))) u32*)g,
      (__attribute__((address_space(3))) u32*)lds, 16, 0, 0);
}

// ---------------- convert x (f32 -> bf16), 8 elems/thread ----------------
__global__ void convert_f32_bf16(const float* __restrict__ in,
                                 u16* __restrict__ out, int n8) {
  int i = blockIdx.x * blockDim.x + threadIdx.x;
  int stride = gridDim.x * blockDim.x;
  for (; i < n8; i += stride) {
    const float4* p = (const float4*)in + (size_t)i * 2;
    float4 a = p[0], b = p[1];
    u16x8 v;
    v[0] = tobf(a.x); v[1] = tobf(a.y); v[2] = tobf(a.z); v[3] = tobf(a.w);
    v[4] = tobf(b.x); v[5] = tobf(b.y); v[6] = tobf(b.z); v[7] = tobf(b.w);
    *(u16x8*)(out + (size_t)i * 8) = v;
  }
}

// ---------------- transpose + cast weights: out[n][k] = in[k][n] ----------
__global__ void transpose_w(const float* __restrict__ in,
                            u16* __restrict__ out, int K, int N) {
  __shared__ float tile[32][33];
  int nbx = N >> 5;
  int bx = blockIdx.x % nbx, by = blockIdx.x / nbx;
  int k0 = by << 5, n0 = bx << 5;
  int tx = threadIdx.x & 31, ty = threadIdx.x >> 5;
#pragma unroll
  for (int j = 0; j < 4; ++j) {
    int row = ty + j * 8;
    tile[row][tx] = in[(size_t)(k0 + row) * N + n0 + tx];
  }
  __syncthreads();
#pragma unroll
  for (int j = 0; j < 4; ++j) {
    int row = ty + j * 8;
    out[(size_t)(n0 + row) * K + k0 + tx] = tobf(tile[tx][row]);
  }
}

// ---------------- GEMM: C[M,N] = A[M,K] * Bt[N,K]^T  (bf16 in, f32 acc) ---
template <int EPI>
__global__ __launch_bounds__(256) void gemm_bt(
    const u16* __restrict__ A, const u16* __restrict__ Bt,
    const float* __restrict__ bias,
    u16* __restrict__ o0, u16* __restrict__ o1, u16* __restrict__ o2,
    float* __restrict__ fo, int M, int N, int K) {
  __shared__ __align__(16) u16 As[128 * 64];
  __shared__ __align__(16) u16 Bs[128 * 64];
  const int tid = threadIdx.x;
  const int lane = tid & 63;
  const int wave = tid >> 6;
  const int nbn = N >> 7;
  const int bm = (int)blockIdx.x / nbn, bn = (int)blockIdx.x % nbn;
  const int m0 = bm << 7, n0 = bn << 7;
  const int wr = wave >> 1, wc = wave & 1;
  const int r15 = lane & 15, g = lane >> 4;

  f32x4 acc[4][4] = {};

  const int nkt = K >> 6;
  for (int kt = 0; kt < nkt; ++kt) {
#pragma unroll
    for (int j = 0; j < 4; ++j) {
      int c = j * 4 + wave;
      int byte0 = c * 1024 + lane * 16;
      int row = byte0 >> 7;
      int colb = (byte0 & 127) ^ ((row & 7) << 4);
      gload_lds16(A + (size_t)(m0 + row) * K + kt * 64 + (colb >> 1),
                  (char*)As + c * 1024);
      gload_lds16(Bt + (size_t)(n0 + row) * K + kt * 64 + (colb >> 1),
                  (char*)Bs + c * 1024);
    }
    __syncthreads();
#pragma unroll
    for (int kk = 0; kk < 64; kk += 32) {
      bf16x8 af[4], bf[4];
#pragma unroll
      for (int i = 0; i < 4; ++i) {
        int rowA = wr * 64 + i * 16 + r15;
        int ca = (kk * 2 + 16 * g) ^ ((rowA & 7) << 4);
        af[i] = *(const bf16x8*)((const char*)As + rowA * 128 + ca);
        int rowB = wc * 64 + i * 16 + r15;
        int cb = (kk * 2 + 16 * g) ^ ((rowB & 7) << 4);
        bf[i] = *(const bf16x8*)((const char*)Bs + rowB * 128 + cb);
      }
#pragma unroll
      for (int i = 0; i < 4; ++i)
#pragma unroll
        for (int j2 = 0; j2 < 4; ++j2)
          acc[i][j2] = __builtin_amdgcn_mfma_f32_16x16x32_bf16(
              af[i], bf[j2], acc[i][j2], 0, 0, 0);
    }
    __syncthreads();
  }
#pragma unroll
  for (int j2 = 0; j2 < 4; ++j2) {
    int n = n0 + wc * 64 + j2 * 16 + r15;
    float bv = bias[n];
#pragma unroll
    for (int i = 0; i < 4; ++i) {
      int mbase = m0 + wr * 64 + i * 16 + g * 4;
#pragma unroll
      for (int rr = 0; rr < 4; ++rr) {
        float val = acc[i][j2][rr] + bv;
        int m = mbase + rr;
        if (EPI == 0) {
          u16 hv = tobf(val);
          int b = m >> 11, t = m & 2047;
          int sec = n >> 10, nn = n & 1023;
          int h = nn >> 6, d = nn & 63;
          if (sec == 0)
            o0[((size_t)((b * 16 + h) * 2048 + t)) * 64 + d] = hv;
          else if (sec == 1)
            o1[((size_t)((b * 16 + h) * 2048 + t)) * 64 + d] = hv;
          else
            o2[((size_t)((b * 16 + h) * 64 + d)) * 2048 + t] = hv;
        } else {
          fo[(size_t)m * N + n] = val;
        }
      }
    }
  }
}

// ---------------- causal flash attention v5 (swapped QK^T + KV-split) -----
// 256 thr / 4 waves; wave owns 32 q-rows (128 q/block). Chunks c<4 run whole
// (<=8 tiles); chunks c>=4 are split into two blocks over the KV range
// ([0,c+1) and [c+1,2c+2), each <=16 tiles) that emit normalized partials
// (y_h bf16, M_h = m + log2 l) combined by attn_combine. Grid 896, heavy
// pieces first. Softmax per-lane scalar (lane owns one q row).
__global__ __launch_bounds__(256) void attn_kernel(
    const u16* __restrict__ qb, const u16* __restrict__ kb,
    const u16* __restrict__ vt, u16* __restrict__ yb,
    u16* __restrict__ party, float* __restrict__ partM) {
  __shared__ __align__(16) u16 Ks[2][64 * 64];
  __shared__ __align__(16) u16 Vs[2][64 * 64];
  const int tid = threadIdx.x;
  const int lane = tid & 63;
  const int w = tid >> 6;                       // 0..3
  const int q31 = lane & 31, hi = lane >> 5;
  const int bx = blockIdx.x;
  const int i = bx >> 5;                        // 0..27, heavy first
  const int bh = bx & 31;
  const bool split = (i < 24);
  const int c = split ? (15 - (i >> 1)) : (27 - i);
  const int h = split ? (i & 1) : 0;
  const int kt0 = (split && h) ? (c + 1) : 0;
  const int ktN = (split && !h) ? (c + 1) : (2 * c + 2);

  const int q0 = c * 128 + w * 32;              // wave's first q row
  const int qmax = q0 + 31;

  // staging: linear LDS dest, pre-swizzled source
  const int srow = tid >> 3;                    // 0..31
  const int scolb = ((tid & 7) * 16) ^ ((srow & 7) << 4);
  const u16* ksrc = kb + ((size_t)bh * 2048 + srow) * 64 + (scolb >> 1);
  const u16* vsrc = vt + ((size_t)bh * 64 + srow) * 2048 + (scolb >> 1);

#define STAGE(buf, kt)                                                     \
  do {                                                                     \
    gload_lds16(ksrc + (size_t)(kt) * 4096, (char*)Ks[buf] + w * 1024);    \
    gload_lds16(ksrc + (size_t)(kt) * 4096 + 32 * 64,                      \
                (char*)Ks[buf] + 4096 + w * 1024);                         \
    gload_lds16(vsrc + (kt) * 64, (char*)Vs[buf] + w * 1024);              \
    gload_lds16(vsrc + (kt) * 64 + 32 * 2048,                              \
                (char*)Vs[buf] + 4096 + w * 1024);                         \
  } while (0)

  // Q fragments: lane holds Q[q0+q31][d = ks*16 + 8*hi .. +8), ks=0..3
  const u16* qrow = qb + ((size_t)bh * 2048 + q0 + q31) * 64;
  bf16x8 aq[4];
#pragma unroll
  for (int ks = 0; ks < 4; ++ks)
    aq[ks] = *(const bf16x8*)(qrow + ks * 16 + 8 * hi);

  f32x16 o0 = {}, o1 = {};      // O^T: lane q=q31; d=(r&3)+8(r>>2)+4hi (+32)
  float m = -INFINITY, l = 0.f; // per-lane (per-q-row) softmax state
  const int qg = q0 + q31;

  STAGE(0, kt0);
  __syncthreads();
  int cur = 0;
  for (int kt = kt0; kt < ktN; ++kt) {
    if (kt + 1 < ktN) STAGE(cur ^ 1, kt + 1);
    if (kt * 64 <= qmax) {
      const char* Kc = (const char*)Ks[cur];
      const char* Vc = (const char*)Vs[cur];
      const int swz = (q31 & 7) << 4;

      // S^T = K Q^T : s0 = kv[0..32), s1 = kv[32..64); col q = lane&31
      f32x16 s0 = {}, s1 = {};
      __builtin_amdgcn_s_setprio(1);
#pragma unroll
      for (int ks = 0; ks < 4; ++ks) {
        int cb = (32 * ks + 16 * hi) ^ swz;
        bf16x8 k0 = *(const bf16x8*)(Kc + q31 * 128 + cb);
        s0 = __builtin_amdgcn_mfma_f32_32x32x16_bf16(k0, aq[ks], s0, 0, 0, 0);
        bf16x8 k1 = *(const bf16x8*)(Kc + (32 + q31) * 128 + cb);
        s1 = __builtin_amdgcn_mfma_f32_32x32x16_bf16(k1, aq[ks], s1, 0, 0, 0);
      }
      __builtin_amdgcn_s_setprio(0);

      // scale + causal mask (log2 domain); in-lane max over 32 values
      const bool anymask = (kt * 64 + 63 > q0);
      float mt = -INFINITY;
#pragma unroll
      for (int r = 0; r < 16; ++r) {
        float sv = s0[r] * SM_SCALE;
        float sw = s1[r] * SM_SCALE;
        if (anymask) {
          int kvg = kt * 64 + (r & 3) + 8 * (r >> 2) + 4 * hi;
          if (kvg > qg) sv = -INFINITY;
          if (kvg + 32 > qg) sw = -INFINITY;
        }
        s0[r] = sv;
        s1[r] = sw;
        mt = fmaxf(mt, fmaxf(sv, sw));
      }
      mt = fmaxf(mt, __shfl_xor(mt, 32, 64));  // combine kv-halves (same q)

      // defer-max: rescale only when row max grew by > 8 (log2 domain)
      if (__any(mt > m + 8.f)) {
        float mnew = fmaxf(m, mt);
        float alpha = exp2f(m - mnew);
        m = mnew;
        l *= alpha;
#pragma unroll
        for (int r = 0; r < 16; ++r) {
          o0[r] *= alpha;
          o1[r] *= alpha;
        }
      }
      // exp (in place) + per-lane partial sum
#pragma unroll
      for (int r = 0; r < 16; ++r) {
        float p0 = exp2f(s0[r] - m);
        float p1 = exp2f(s1[r] - m);
        l += p0 + p1;
        s0[r] = p0;
        s1[r] = p1;
      }
      // pack to bf16 pairs then redistribute halves across lane<32/>=32
      u32 W[16];
#pragma unroll
      for (int i2 = 0; i2 < 8; ++i2) {
        asm("v_cvt_pk_bf16_f32 %0, %1, %2"
            : "=v"(W[i2]) : "v"(s0[2 * i2]), "v"(s0[2 * i2 + 1]));
        asm("v_cvt_pk_bf16_f32 %0, %1, %2"
            : "=v"(W[8 + i2]) : "v"(s1[2 * i2]), "v"(s1[2 * i2 + 1]));
      }
#pragma unroll
      for (int b4 = 0; b4 < 16; b4 += 4) {
        asm("v_permlane32_swap_b32 %0, %1" : "+v"(W[b4]), "+v"(W[b4 + 2]));
        asm("v_permlane32_swap_b32 %0, %1" : "+v"(W[b4 + 1]), "+v"(W[b4 + 3]));
      }
      // PV: O^T += V^T * P^T  (lane: row d, col q)
      __builtin_amdgcn_s_setprio(1);
#pragma unroll
      for (int ks = 0; ks < 4; ++ks) {
        u32x4 pwv = {W[4 * ks], W[4 * ks + 1], W[4 * ks + 2], W[4 * ks + 3]};
        bf16x8 pf = __builtin_bit_cast(bf16x8, pwv);
        int cb = (32 * ks + 16 * hi) ^ swz;
        bf16x8 v0 = *(const bf16x8*)(Vc + q31 * 128 + cb);
        o0 = __builtin_amdgcn_mfma_f32_32x32x16_bf16(v0, pf, o0, 0, 0, 0);
        bf16x8 v1 = *(const bf16x8*)(Vc + (32 + q31) * 128 + cb);
        o1 = __builtin_amdgcn_mfma_f32_32x32x16_bf16(v1, pf, o1, 0, 0, 0);
      }
      __builtin_amdgcn_s_setprio(0);
    }
    __syncthreads();
    cur ^= 1;
  }
#undef STAGE

  // final: combine partner's partial sum (other kv half, same q)
  l += __shfl_xor(l, 32, 64);
  float inv = 1.0f / l;

  if (!split) {
    // direct: y[b, t, h*64+d] bf16
    int b = bh >> 4, hd = bh & 15;
    u32* dst = (u32*)(yb + ((size_t)b * 2048 + q0 + q31) * 1024 + hd * 64);
#pragma unroll
    for (int r = 0; r < 16; r += 2) {
      int d = (r & 3) + 8 * (r >> 2) + 4 * hi;
      dst[d >> 1] = (u32)tobf(o0[r] * inv) | ((u32)tobf(o0[r + 1] * inv) << 16);
      dst[(d + 32) >> 1] =
          (u32)tobf(o1[r] * inv) | ((u32)tobf(o1[r + 1] * inv) << 16);
    }
  } else {
    // partial: normalized y_h (bf16) + M_h = m + log2(l) (f32)
    int pidx = (((c - 4) * 32 + bh) * 2 + h);
    int row = w * 32 + q31;
    u32* dst = (u32*)(party + ((size_t)pidx * 128 + row) * 64);
#pragma unroll
    for (int r = 0; r < 16; r += 2) {
      int d = (r & 3) + 8 * (r >> 2) + 4 * hi;
      dst[d >> 1] = (u32)tobf(o0[r] * inv) | ((u32)tobf(o0[r + 1] * inv) << 16);
      dst[(d + 32) >> 1] =
          (u32)tobf(o1[r] * inv) | ((u32)tobf(o1[r + 1] * inv) << 16);
    }
    if (hi == 0) partM[pidx * 128 + row] = m + log2f(l);
  }
}

// ---------------- combine split partials ---------------------------------
__global__ __launch_bounds__(256) void attn_combine(
    const u16* __restrict__ party, const float* __restrict__ partM,
    u16* __restrict__ yb) {
  const int cb = blockIdx.x;            // (c-4)*32 + bh, 0..383
  const int c = 4 + (cb >> 5), bh = cb & 31;
  const int tid = threadIdx.x;
  const int row = tid >> 1, off = (tid & 1) * 32;
  const float M0 = partM[(cb * 2 + 0) * 128 + row];
  const float M1 = partM[(cb * 2 + 1) * 128 + row];
  const float Mm = fmaxf(M0, M1);
  float w0 = exp2f(M0 - Mm), w1 = exp2f(M1 - Mm);
  const float inv = 1.f / (w0 + w1);
  w0 *= inv;
  w1 *= inv;
  const u16* p0 = party + ((size_t)(cb * 2 + 0) * 128 + row) * 64 + off;
  const u16* p1 = party + ((size_t)(cb * 2 + 1) * 128 + row) * 64 + off;
  const int b = bh >> 4, head = bh & 15, t = c * 128 + row;
  u16* dst = yb + ((size_t)b * 2048 + t) * 1024 + head * 64 + off;
#pragma unroll
  for (int j = 0; j < 32; j += 8) {
    u16x8 a = *(const u16x8*)(p0 + j);
    u16x8 bv = *(const u16x8*)(p1 + j);
    u16x8 ov;
#pragma unroll
    for (int e = 0; e < 8; ++e)
      ov[e] = tobf(frombf(a[e]) * w0 + frombf(bv[e]) * w1);
    *(u16x8*)(dst + j) = ov;
  }
}

extern "C" void kernel_launch(void* const* d_in, const int* in_sizes, int n_in,
                              void* d_out, int out_size, void* d_ws,
                              size_t ws_size, hipStream_t stream) {
  const float* x = (const float*)d_in[0];
  const float* w_attn = (const float*)d_in[1];
  const float* b_attn = (const float*)d_in[2];
  const float* w_proj = (const float*)d_in[3];
  const float* b_proj = (const float*)d_in[4];
  float* out = (float*)d_out;
  char* ws = (char*)d_ws;

  u16* xb = (u16*)ws;                          // 8 MB  [4096][1024] (dead after GEMM1)
  u16* wat = (u16*)(ws + (8ull << 20));        // 6 MB  [3072][1024] (dead after GEMM1)
  u16* wpt = (u16*)(ws + (14ull << 20));       // 2 MB  [1024][1024]
  u16* qbuf = (u16*)(ws + (16ull << 20));      // 8 MB  [B,H,T,D]
  u16* kbuf = (u16*)(ws + (24ull << 20));      // 8 MB  [B,H,T,D]
  u16* vtb = (u16*)(ws + (32ull << 20));       // 8 MB  [B,H,D,T]
  u16* yb = (u16*)(ws + (40ull << 20));        // 8 MB  [4096][1024]
  // partials reuse the xb/wat region (dead during attn):
  u16* party = (u16*)ws;                       // 12.6 MB: [384*2][128][64] bf16
  float* partM = (float*)(ws + (13ull << 20)); // 0.4 MB: [384*2][128] f32

  convert_f32_bf16<<<2048, 256, 0, stream>>>(x, xb, (4096 * 1024) / 8);
  transpose_w<<<3072, 256, 0, stream>>>(w_attn, wat, 1024, 3072);
  transpose_w<<<1024, 256, 0, stream>>>(w_proj, wpt, 1024, 1024);
  gemm_bt<0><<<32 * 24, 256, 0, stream>>>(xb, wat, b_attn, qbuf, kbuf, vtb,
                                          nullptr, 4096, 3072, 1024);
  attn_kernel<<<896, 256, 0, stream>>>(qbuf, kbuf, vtb, yb, party, partM);
  attn_combine<<<384, 256, 0, stream>>>(party, partM, yb);
  gemm_bt<1><<<32 * 8, 256, 0, stream>>>(yb, wpt, b_proj, nullptr, nullptr,
                                         nullptr, out, 4096, 1024, 1024);
}

// Round 6
// 152.123 us; speedup vs baseline: 1.1099x; 1.0536x over previous
//
#include <hip/hip_runtime.h>
#include <hip/hip_bf16.h>

typedef __bf16 bf16x8 __attribute__((ext_vector_type(8)));
typedef float f32x4 __attribute__((ext_vector_type(4)));
typedef float f32x16 __attribute__((ext_vector_type(16)));
typedef unsigned short u16;
typedef unsigned int u32;
typedef u16 u16x8 __attribute__((ext_vector_type(8)));
typedef u32 u32x4 __attribute__((ext_vector_type(4)));

#define SM_SCALE 0.1803368801111244f  // (1/8) * log2(e), folded into Q

// f32 -> bf16 round-to-nearest-even
__device__ inline u16 tobf(float f) {
  u32 u = __builtin_bit_cast(u32, f);
  u32 r = (u + 0x7fffu + ((u >> 16) & 1u)) >> 16;
  return (u16)r;
}

__device__ inline float frombf(u16 h) {
  return __builtin_bit_cast(float, (u32)h << 16);
}

__device__ inline void gload_lds16(const void* g, void* lds) {
  __builtin_amdgcn_global_load_lds(
      (const __attribute__((address_space(1))) u32*)g,
      (__attribute__((address_space(3))) u32*)lds, 16, 0, 0);
}

// ---------------- convert x (f32 -> bf16), 8 elems/thread ----------------
__global__ void convert_f32_bf16(const float* __restrict__ in,
                                 u16* __restrict__ out, int n8) {
  int i = blockIdx.x * blockDim.x + threadIdx.x;
  int stride = gridDim.x * blockDim.x;
  for (; i < n8; i += stride) {
    const float4* p = (const float4*)in + (size_t)i * 2;
    float4 a = p[0], b = p[1];
    u16x8 v;
    v[0] = tobf(a.x); v[1] = tobf(a.y); v[2] = tobf(a.z); v[3] = tobf(a.w);
    v[4] = tobf(b.x); v[5] = tobf(b.y); v[6] = tobf(b.z); v[7] = tobf(b.w);
    *(u16x8*)(out + (size_t)i * 8) = v;
  }
}

// ---------------- transpose + cast weights: out[n][k] = in[k][n] ----------
__global__ void transpose_w(const float* __restrict__ in,
                            u16* __restrict__ out, int K, int N) {
  __shared__ float tile[32][33];
  int nbx = N >> 5;
  int bx = blockIdx.x % nbx, by = blockIdx.x / nbx;
  int k0 = by << 5, n0 = bx << 5;
  int tx = threadIdx.x & 31, ty = threadIdx.x >> 5;
#pragma unroll
  for (int j = 0; j < 4; ++j) {
    int row = ty + j * 8;
    tile[row][tx] = in[(size_t)(k0 + row) * N + n0 + tx];
  }
  __syncthreads();
#pragma unroll
  for (int j = 0; j < 4; ++j) {
    int row = ty + j * 8;
    out[(size_t)(n0 + row) * K + k0 + tx] = tobf(tile[tx][row]);
  }
}

// ---------------- GEMM: C[M,N] = A[M,K] * Bt[N,K]^T  (bf16 in, f32 acc) ---
// EPI 0: q scaled by SM_SCALE, scatter q/k/vT bf16 (+bias). EPI 1: f32 (+bias)
template <int EPI>
__global__ __launch_bounds__(256) void gemm_bt(
    const u16* __restrict__ A, const u16* __restrict__ Bt,
    const float* __restrict__ bias,
    u16* __restrict__ o0, u16* __restrict__ o1, u16* __restrict__ o2,
    float* __restrict__ fo, int M, int N, int K) {
  __shared__ __align__(16) u16 As[128 * 64];
  __shared__ __align__(16) u16 Bs[128 * 64];
  const int tid = threadIdx.x;
  const int lane = tid & 63;
  const int wave = tid >> 6;
  const int nbn = N >> 7;
  const int bm = (int)blockIdx.x / nbn, bn = (int)blockIdx.x % nbn;
  const int m0 = bm << 7, n0 = bn << 7;
  const int wr = wave >> 1, wc = wave & 1;
  const int r15 = lane & 15, g = lane >> 4;

  f32x4 acc[4][4] = {};

  const int nkt = K >> 6;
  for (int kt = 0; kt < nkt; ++kt) {
#pragma unroll
    for (int j = 0; j < 4; ++j) {
      int c = j * 4 + wave;
      int byte0 = c * 1024 + lane * 16;
      int row = byte0 >> 7;
      int colb = (byte0 & 127) ^ ((row & 7) << 4);
      gload_lds16(A + (size_t)(m0 + row) * K + kt * 64 + (colb >> 1),
                  (char*)As + c * 1024);
      gload_lds16(Bt + (size_t)(n0 + row) * K + kt * 64 + (colb >> 1),
                  (char*)Bs + c * 1024);
    }
    __syncthreads();
#pragma unroll
    for (int kk = 0; kk < 64; kk += 32) {
      bf16x8 af[4], bf[4];
#pragma unroll
      for (int i = 0; i < 4; ++i) {
        int rowA = wr * 64 + i * 16 + r15;
        int ca = (kk * 2 + 16 * g) ^ ((rowA & 7) << 4);
        af[i] = *(const bf16x8*)((const char*)As + rowA * 128 + ca);
        int rowB = wc * 64 + i * 16 + r15;
        int cb = (kk * 2 + 16 * g) ^ ((rowB & 7) << 4);
        bf[i] = *(const bf16x8*)((const char*)Bs + rowB * 128 + cb);
      }
#pragma unroll
      for (int i = 0; i < 4; ++i)
#pragma unroll
        for (int j2 = 0; j2 < 4; ++j2)
          acc[i][j2] = __builtin_amdgcn_mfma_f32_16x16x32_bf16(
              af[i], bf[j2], acc[i][j2], 0, 0, 0);
    }
    __syncthreads();
  }
#pragma unroll
  for (int j2 = 0; j2 < 4; ++j2) {
    int n = n0 + wc * 64 + j2 * 16 + r15;
    float bv = bias[n];
#pragma unroll
    for (int i = 0; i < 4; ++i) {
      int mbase = m0 + wr * 64 + i * 16 + g * 4;
#pragma unroll
      for (int rr = 0; rr < 4; ++rr) {
        float val = acc[i][j2][rr] + bv;
        int m = mbase + rr;
        if (EPI == 0) {
          int b = m >> 11, t = m & 2047;
          int sec = n >> 10, nn = n & 1023;
          int h = nn >> 6, d = nn & 63;
          if (sec == 0)
            o0[((size_t)((b * 16 + h) * 2048 + t)) * 64 + d] =
                tobf(val * SM_SCALE);
          else if (sec == 1)
            o1[((size_t)((b * 16 + h) * 2048 + t)) * 64 + d] = tobf(val);
          else
            o2[((size_t)((b * 16 + h) * 64 + d)) * 2048 + t] = tobf(val);
        } else {
          fo[(size_t)m * N + n] = val;
        }
      }
    }
  }
}

// ---------------- piece tables (pid 0..33) --------------------------------
// c: q-chunk; [kt0,ktN): kv tile range; slot: -2 direct, -1 partial->yb,
// >=0 partial->party slot.
static __device__ const signed char PT_C[34] =
    {15,15,15,15,14,14,14,13,13,13,12,12,12,11,11,11,10,10,10,9,9,8,8,7,7,6,6,5,5,4,3,2,1,0};
static __device__ const signed char PT_K0[34] =
    {0,8,16,24,0,10,20,0,9,18,0,8,17,0,8,16,0,7,14,0,10,0,9,0,8,0,7,0,6,0,0,0,0,0};
static __device__ const signed char PT_KN[34] =
    {8,16,24,32,10,20,30,9,18,28,8,17,26,8,16,24,7,14,22,10,20,9,18,8,16,7,14,6,12,10,8,6,4,2};
static __device__ const signed char PT_SL[34] =
    {-1,0,1,2,-1,3,4,-1,5,6,-1,7,8,-1,9,10,-1,11,12,-1,13,-1,14,-1,15,-1,16,-1,17,-2,-2,-2,-2,-2};

// ---------------- causal flash attention v6 -------------------------------
// 256 thr / 4 waves; wave owns 32 q-rows; KV tiles 64; dbuf staging; pieces
// of <=10 tiles from the table above; swapped mfma(K,Q) softmax (per-lane
// scalar m,l); Q pre-scaled by SM_SCALE; defer-max THR=8 (log2 domain).
__global__ __launch_bounds__(256) void attn_kernel(
    const u16* __restrict__ qb, const u16* __restrict__ kb,
    const u16* __restrict__ vt, u16* __restrict__ yb,
    u16* __restrict__ party, float* __restrict__ partM) {
  __shared__ __align__(16) u16 Ks[2][64 * 64];
  __shared__ __align__(16) u16 Vs[2][64 * 64];
  const int tid = threadIdx.x;
  const int lane = tid & 63;
  const int w = tid >> 6;                       // 0..3
  const int q31 = lane & 31, hi = lane >> 5;
  const int bx = blockIdx.x;
  const int pid = bx >> 5, bh = bx & 31;
  const int c = PT_C[pid];
  const int kt0 = PT_K0[pid], ktN = PT_KN[pid];
  const int slot = PT_SL[pid];

  const int q0 = c * 128 + w * 32;              // wave's first q row
  const int qmax = q0 + 31;
  const int qg = q0 + q31;                      // this lane's q row

  // staging: linear LDS dest, pre-swizzled source
  const int srow = tid >> 3;                    // 0..31
  const int scolb = ((tid & 7) * 16) ^ ((srow & 7) << 4);
  const u16* ksrc = kb + ((size_t)bh * 2048 + srow) * 64 + (scolb >> 1);
  const u16* vsrc = vt + ((size_t)bh * 64 + srow) * 2048 + (scolb >> 1);

#define STAGE(buf, kt)                                                     \
  do {                                                                     \
    gload_lds16(ksrc + (size_t)(kt) * 4096, (char*)Ks[buf] + w * 1024);    \
    gload_lds16(ksrc + (size_t)(kt) * 4096 + 32 * 64,                      \
                (char*)Ks[buf] + 4096 + w * 1024);                         \
    gload_lds16(vsrc + (kt) * 64, (char*)Vs[buf] + w * 1024);              \
    gload_lds16(vsrc + (kt) * 64 + 32 * 2048,                              \
                (char*)Vs[buf] + 4096 + w * 1024);                         \
  } while (0)

  // Q fragments: lane holds Q[qg][d = ks*16 + 8*hi .. +8), ks=0..3
  const u16* qrow = qb + ((size_t)bh * 2048 + qg) * 64;
  bf16x8 aq[4];
#pragma unroll
  for (int ks = 0; ks < 4; ++ks)
    aq[ks] = *(const bf16x8*)(qrow + ks * 16 + 8 * hi);

  f32x16 o0 = {}, o1 = {};      // O^T: lane q=q31; d=(r&3)+8(r>>2)+4hi (+32)
  float m = -INFINITY, l = 0.f; // per-lane (per-q-row) softmax state

  STAGE(0, kt0);
  __syncthreads();
  int cur = 0;
  for (int kt = kt0; kt < ktN; ++kt) {
    if (kt + 1 < ktN) STAGE(cur ^ 1, kt + 1);
    if (kt * 64 <= qmax) {
      const char* Kc = (const char*)Ks[cur];
      const char* Vc = (const char*)Vs[cur];
      const int swz = (q31 & 7) << 4;

      // S^T = K Q^T : s0 = kv[0..32), s1 = kv[32..64); col q = lane&31
      f32x16 s0 = {}, s1 = {};
      __builtin_amdgcn_s_setprio(1);
#pragma unroll
      for (int ks = 0; ks < 4; ++ks) {
        int cb = (32 * ks + 16 * hi) ^ swz;
        bf16x8 k0 = *(const bf16x8*)(Kc + q31 * 128 + cb);
        s0 = __builtin_amdgcn_mfma_f32_32x32x16_bf16(k0, aq[ks], s0, 0, 0, 0);
        bf16x8 k1 = *(const bf16x8*)(Kc + (32 + q31) * 128 + cb);
        s1 = __builtin_amdgcn_mfma_f32_32x32x16_bf16(k1, aq[ks], s1, 0, 0, 0);
      }
      __builtin_amdgcn_s_setprio(0);

      // causal mask: only the diagonal tile(s) of the wave need it
      if (kt * 64 + 63 > q0) {
        const int thr = qg - kt * 64;
#pragma unroll
        for (int r = 0; r < 16; ++r) {
          const int off = (r & 3) + 8 * (r >> 2) + 4 * hi;
          if (off > thr) s0[r] = -INFINITY;
          if (off + 32 > thr) s1[r] = -INFINITY;
        }
      }
      // tree max over 32 in-lane values
      f32x16 mx;
#pragma unroll
      for (int r = 0; r < 16; ++r) mx[r] = fmaxf(s0[r], s1[r]);
#pragma unroll
      for (int st = 8; st >= 1; st >>= 1)
#pragma unroll
        for (int r = 0; r < st; ++r) mx[r] = fmaxf(mx[r], mx[r + st]);
      float mt = fmaxf(mx[0], __shfl_xor(mx[0], 32, 64));

      if (kt == kt0) {
        m = mt;  // first tile: no rescale needed (o == 0)
      } else if (__any(mt > m + 8.f)) {
        float mnew = fmaxf(m, mt);
        float alpha = exp2f(m - mnew);
        m = mnew;
        l *= alpha;
#pragma unroll
        for (int r = 0; r < 16; ++r) {
          o0[r] *= alpha;
          o1[r] *= alpha;
        }
      }
      // exp (in place) + 4-accumulator partial sum
#pragma unroll
      for (int r = 0; r < 16; ++r) {
        s0[r] = exp2f(s0[r] - m);
        s1[r] = exp2f(s1[r] - m);
      }
      {
        float la = 0.f, lb = 0.f, lc2 = 0.f, ld = 0.f;
#pragma unroll
        for (int r = 0; r < 16; r += 2) {
          la += s0[r];
          lb += s0[r + 1];
          lc2 += s1[r];
          ld += s1[r + 1];
        }
        l += (la + lb) + (lc2 + ld);
      }
      // pack to bf16 pairs then redistribute halves across lane<32/>=32
      u32 W[16];
#pragma unroll
      for (int i2 = 0; i2 < 8; ++i2) {
        asm("v_cvt_pk_bf16_f32 %0, %1, %2"
            : "=v"(W[i2]) : "v"(s0[2 * i2]), "v"(s0[2 * i2 + 1]));
        asm("v_cvt_pk_bf16_f32 %0, %1, %2"
            : "=v"(W[8 + i2]) : "v"(s1[2 * i2]), "v"(s1[2 * i2 + 1]));
      }
#pragma unroll
      for (int b4 = 0; b4 < 16; b4 += 4) {
        asm("v_permlane32_swap_b32 %0, %1" : "+v"(W[b4]), "+v"(W[b4 + 2]));
        asm("v_permlane32_swap_b32 %0, %1" : "+v"(W[b4 + 1]), "+v"(W[b4 + 3]));
      }
      // PV: O^T += V^T * P^T  (lane: row d, col q)
      __builtin_amdgcn_s_setprio(1);
#pragma unroll
      for (int ks = 0; ks < 4; ++ks) {
        u32x4 pwv = {W[4 * ks], W[4 * ks + 1], W[4 * ks + 2], W[4 * ks + 3]};
        bf16x8 pf = __builtin_bit_cast(bf16x8, pwv);
        int cb = (32 * ks + 16 * hi) ^ swz;
        bf16x8 v0 = *(const bf16x8*)(Vc + q31 * 128 + cb);
        o0 = __builtin_amdgcn_mfma_f32_32x32x16_bf16(v0, pf, o0, 0, 0, 0);
        bf16x8 v1 = *(const bf16x8*)(Vc + (32 + q31) * 128 + cb);
        o1 = __builtin_amdgcn_mfma_f32_32x32x16_bf16(v1, pf, o1, 0, 0, 0);
      }
      __builtin_amdgcn_s_setprio(0);
    }
    __syncthreads();
    cur ^= 1;
  }
#undef STAGE

  // final: combine partner's partial sum (other kv half, same q)
  l += __shfl_xor(l, 32, 64);
  float inv = 1.0f / l;

  // destination: party slot (slot>=0) or yb (direct & partial-0)
  u32* dst;
  if (slot >= 0) {
    dst = (u32*)(party +
                 ((size_t)((slot * 32 + bh) * 128 + w * 32 + q31)) * 64);
  } else {
    int b = bh >> 4, hd = bh & 15;
    dst = (u32*)(yb + ((size_t)b * 2048 + qg) * 1024 + hd * 64);
  }
#pragma unroll
  for (int r = 0; r < 16; r += 2) {
    int d = (r & 3) + 8 * (r >> 2) + 4 * hi;
    dst[d >> 1] = (u32)tobf(o0[r] * inv) | ((u32)tobf(o0[r + 1] * inv) << 16);
    dst[(d + 32) >> 1] =
        (u32)tobf(o1[r] * inv) | ((u32)tobf(o1[r + 1] * inv) << 16);
  }
  if (slot != -2 && hi == 0)
    partM[(pid * 32 + bh) * 128 + w * 32 + q31] = m + log2f(l);
}

// ---------------- combine split partials ----------------------------------
// groups c=15..5 (ci=0..10); partial 0 lives in yb, partials 1..P-1 in party.
static __device__ const signed char CB_PID[11] = {0,4,7,10,13,16,19,21,23,25,27};
static __device__ const signed char CB_P[11]   = {4,3,3,3,3,3,2,2,2,2,2};
static __device__ const signed char CB_SL[11]  = {0,3,5,7,9,11,13,14,15,16,17};

__global__ __launch_bounds__(256) void attn_combine(
    const u16* __restrict__ party, const float* __restrict__ partM,
    u16* __restrict__ yb) {
  const int gi = blockIdx.x;                  // 0..351
  const int ci = gi >> 5, bh = gi & 31;
  const int c = 15 - ci;
  const int pidb = CB_PID[ci], P = CB_P[ci], slb = CB_SL[ci];
  const int row = threadIdx.x >> 1, off = (threadIdx.x & 1) * 32;

  const float M0 = partM[((pidb + 0) * 32 + bh) * 128 + row];
  const float M1 = partM[((pidb + 1) * 32 + bh) * 128 + row];
  const float M2 = (P > 2) ? partM[((pidb + 2) * 32 + bh) * 128 + row] : -INFINITY;
  const float M3 = (P > 3) ? partM[((pidb + 3) * 32 + bh) * 128 + row] : -INFINITY;
  const float Mm = fmaxf(fmaxf(M0, M1), fmaxf(M2, M3));
  const float w0 = exp2f(M0 - Mm), w1 = exp2f(M1 - Mm);
  const float w2 = exp2f(M2 - Mm), w3 = exp2f(M3 - Mm);
  const float inv = 1.f / (w0 + w1 + w2 + w3);

  const int b = bh >> 4, head = bh & 15, t = c * 128 + row;
  u16* y = yb + ((size_t)b * 2048 + t) * 1024 + head * 64 + off;

  float acc[32];
#pragma unroll
  for (int j = 0; j < 4; ++j) {
    u16x8 a = *(const u16x8*)(y + j * 8);
#pragma unroll
    for (int e = 0; e < 8; ++e) acc[j * 8 + e] = frombf(a[e]) * w0;
  }
  {
    const u16* p1 = party + ((size_t)((slb + 0) * 32 + bh) * 128 + row) * 64 + off;
#pragma unroll
    for (int j = 0; j < 4; ++j) {
      u16x8 a = *(const u16x8*)(p1 + j * 8);
#pragma unroll
      for (int e = 0; e < 8; ++e) acc[j * 8 + e] += frombf(a[e]) * w1;
    }
  }
  if (P > 2) {
    const u16* p2 = party + ((size_t)((slb + 1) * 32 + bh) * 128 + row) * 64 + off;
#pragma unroll
    for (int j = 0; j < 4; ++j) {
      u16x8 a = *(const u16x8*)(p2 + j * 8);
#pragma unroll
      for (int e = 0; e < 8; ++e) acc[j * 8 + e] += frombf(a[e]) * w2;
    }
  }
  if (P > 3) {
    const u16* p3 = party + ((size_t)((slb + 2) * 32 + bh) * 128 + row) * 64 + off;
#pragma unroll
    for (int j = 0; j < 4; ++j) {
      u16x8 a = *(const u16x8*)(p3 + j * 8);
#pragma unroll
      for (int e = 0; e < 8; ++e) acc[j * 8 + e] += frombf(a[e]) * w3;
    }
  }
#pragma unroll
  for (int j = 0; j < 4; ++j) {
    u16x8 ov;
#pragma unroll
    for (int e = 0; e < 8; ++e) ov[e] = tobf(acc[j * 8 + e] * inv);
    *(u16x8*)(y + j * 8) = ov;
  }
}

extern "C" void kernel_launch(void* const* d_in, const int* in_sizes, int n_in,
                              void* d_out, int out_size, void* d_ws,
                              size_t ws_size, hipStream_t stream) {
  const float* x = (const float*)d_in[0];
  const float* w_attn = (const float*)d_in[1];
  const float* b_attn = (const float*)d_in[2];
  const float* w_proj = (const float*)d_in[3];
  const float* b_proj = (const float*)d_in[4];
  float* out = (float*)d_out;
  char* ws = (char*)d_ws;

  u16* xb = (u16*)ws;                          // 8 MB [4096][1024] (dead after GEMM1)
  u16* wat = (u16*)(ws + (8ull << 20));        // 6 MB (dead after GEMM1)
  u16* wpt = (u16*)(ws + (14ull << 20));       // 2 MB (alive until GEMM2)
  u16* qbuf = (u16*)(ws + (16ull << 20));      // 8 MB [B,H,T,D] (q pre-scaled)
  u16* kbuf = (u16*)(ws + (24ull << 20));      // 8 MB [B,H,T,D]
  u16* vtb = (u16*)(ws + (32ull << 20));       // 8 MB [B,H,D,T]
  u16* yb = (u16*)(ws + (40ull << 20));        // 8 MB [4096][1024]
  // partials reuse dead xb/wat region [0,14 MB):
  u16* party = (u16*)ws;                       // 9.0 MB: 576 slots [128][64] bf16
  float* partM = (float*)(ws + (10ull << 20)); // 0.56 MB: [34*32][128] f32

  convert_f32_bf16<<<2048, 256, 0, stream>>>(x, xb, (4096 * 1024) / 8);
  transpose_w<<<3072, 256, 0, stream>>>(w_attn, wat, 1024, 3072);
  transpose_w<<<1024, 256, 0, stream>>>(w_proj, wpt, 1024, 1024);
  gemm_bt<0><<<32 * 24, 256, 0, stream>>>(xb, wat, b_attn, qbuf, kbuf, vtb,
                                          nullptr, 4096, 3072, 1024);
  attn_kernel<<<34 * 32, 256, 0, stream>>>(qbuf, kbuf, vtb, yb, party, partM);
  attn_combine<<<352, 256, 0, stream>>>(party, partM, yb);
  gemm_bt<1><<<32 * 8, 256, 0, stream>>>(yb, wpt, b_proj, nullptr, nullptr,
                                         nullptr, out, 4096, 1024, 1024);
}

// Round 7
// 122.933 us; speedup vs baseline: 1.3735x; 1.2374x over previous
//
#include <hip/hip_runtime.h>
#include <hip/hip_bf16.h>

typedef __bf16 bf16x8 __attribute__((ext_vector_type(8)));
typedef float f32x4 __attribute__((ext_vector_type(4)));
typedef float f32x16 __attribute__((ext_vector_type(16)));
typedef unsigned short u16;
typedef unsigned int u32;
typedef u16 u16x8 __attribute__((ext_vector_type(8)));
typedef u32 u32x4 __attribute__((ext_vector_type(4)));

#define SM_SCALE 0.1803368801111244f  // (1/8) * log2(e), folded into Q

// f32 -> bf16 round-to-nearest-even
__device__ inline u16 tobf(float f) {
  u32 u = __builtin_bit_cast(u32, f);
  u32 r = (u + 0x7fffu + ((u >> 16) & 1u)) >> 16;
  return (u16)r;
}

__device__ inline float frombf(u16 h) {
  return __builtin_bit_cast(float, (u32)h << 16);
}

__device__ inline void gload_lds16(const void* g, void* lds) {
  __builtin_amdgcn_global_load_lds(
      (const __attribute__((address_space(1))) u32*)g,
      (__attribute__((address_space(3))) u32*)lds, 16, 0, 0);
}

// ---------------- convert x (f32 -> bf16), 8 elems/thread ----------------
__global__ void convert_f32_bf16(const float* __restrict__ in,
                                 u16* __restrict__ out, int n8) {
  int i = blockIdx.x * blockDim.x + threadIdx.x;
  int stride = gridDim.x * blockDim.x;
  for (; i < n8; i += stride) {
    const float4* p = (const float4*)in + (size_t)i * 2;
    float4 a = p[0], b = p[1];
    u16x8 v;
    v[0] = tobf(a.x); v[1] = tobf(a.y); v[2] = tobf(a.z); v[3] = tobf(a.w);
    v[4] = tobf(b.x); v[5] = tobf(b.y); v[6] = tobf(b.z); v[7] = tobf(b.w);
    *(u16x8*)(out + (size_t)i * 8) = v;
  }
}

// ---------------- transpose + cast weights: out[n][k] = in[k][n] ----------
__global__ void transpose_w(const float* __restrict__ in,
                            u16* __restrict__ out, int K, int N) {
  __shared__ float tile[32][33];
  int nbx = N >> 5;
  int bx = blockIdx.x % nbx, by = blockIdx.x / nbx;
  int k0 = by << 5, n0 = bx << 5;
  int tx = threadIdx.x & 31, ty = threadIdx.x >> 5;
#pragma unroll
  for (int j = 0; j < 4; ++j) {
    int row = ty + j * 8;
    tile[row][tx] = in[(size_t)(k0 + row) * N + n0 + tx];
  }
  __syncthreads();
#pragma unroll
  for (int j = 0; j < 4; ++j) {
    int row = ty + j * 8;
    out[(size_t)(n0 + row) * K + k0 + tx] = tobf(tile[tx][row]);
  }
}

// ---------------- GEMM: C[M,N] = A[M,K] * Bt[N,K]^T  (bf16 in, f32 acc) ---
// BM=128, BN in {192, 64}. True 2-phase double-buffered staging: issue next
// K-tile's global_load_lds BEFORE computing current tile; one vmcnt(0)+barrier
// per K-tile. XCD-bijective blockIdx swizzle (grid % 8 == 0).
// EPI 0: q scaled by SM_SCALE, scatter q/k/vT bf16 (+bias). EPI 1: f32 (+bias)
template <int EPI, int BN>
__global__ __launch_bounds__(256) void gemm_bt(
    const u16* __restrict__ A, const u16* __restrict__ Bt,
    const float* __restrict__ bias,
    u16* __restrict__ o0, u16* __restrict__ o1, u16* __restrict__ o2,
    float* __restrict__ fo, int M, int N, int K) {
  constexpr int NF = BN / 32;   // B-frags per wave per kk; also B stage iters
  __shared__ __align__(16) u16 As[2][128 * 64];
  __shared__ __align__(16) u16 Bs[2][BN * 64];
  const int tid = threadIdx.x;
  const int lane = tid & 63;
  const int wave = tid >> 6;
  const int nbn = N / BN;
  int bid = (int)blockIdx.x;
  const int cpx = (int)gridDim.x >> 3;
  bid = (bid & 7) * cpx + (bid >> 3);      // XCD-contiguous chunks
  const int bm = bid / nbn, bn = bid % nbn;
  const int m0 = bm << 7, n0 = bn * BN;
  const int wr = wave >> 1, wc = wave & 1;
  const int r15 = lane & 15, g = lane >> 4;

  f32x4 acc[4][NF] = {};

#define GSTAGE(buf, kt)                                                    \
  do {                                                                     \
    _Pragma("unroll")                                                      \
    for (int j = 0; j < 4; ++j) {                                          \
      int c = j * 4 + wave;                                                \
      int byte0 = c * 1024 + lane * 16;                                    \
      int row = byte0 >> 7;                                                \
      int colb = (byte0 & 127) ^ ((row & 7) << 4);                         \
      gload_lds16(A + (size_t)(m0 + row) * K + (kt) * 64 + (colb >> 1),    \
                  (char*)As[(buf)] + c * 1024);                            \
    }                                                                      \
    _Pragma("unroll")                                                      \
    for (int j = 0; j < NF; ++j) {                                         \
      int c = j * 4 + wave;                                                \
      int byte0 = c * 1024 + lane * 16;                                    \
      int row = byte0 >> 7;                                                \
      int colb = (byte0 & 127) ^ ((row & 7) << 4);                         \
      gload_lds16(Bt + (size_t)(n0 + row) * K + (kt) * 64 + (colb >> 1),   \
                  (char*)Bs[(buf)] + c * 1024);                            \
    }                                                                      \
  } while (0)

  const int nkt = K >> 6;
  GSTAGE(0, 0);
  asm volatile("s_waitcnt vmcnt(0)");
  __syncthreads();
  for (int kt = 0; kt < nkt; ++kt) {
    const int cur = kt & 1;
    if (kt + 1 < nkt) GSTAGE(cur ^ 1, kt + 1);
#pragma unroll
    for (int kk = 0; kk < 2; ++kk) {
      bf16x8 af[4], bf[NF];
#pragma unroll
      for (int i = 0; i < 4; ++i) {
        int rowA = wr * 64 + i * 16 + r15;
        int ca = (kk * 64 + 16 * g) ^ ((rowA & 7) << 4);
        af[i] = *(const bf16x8*)((const char*)As[cur] + rowA * 128 + ca);
      }
#pragma unroll
      for (int j2 = 0; j2 < NF; ++j2) {
        int rowB = wc * (BN / 2) + j2 * 16 + r15;
        int cb = (kk * 64 + 16 * g) ^ ((rowB & 7) << 4);
        bf[j2] = *(const bf16x8*)((const char*)Bs[cur] + rowB * 128 + cb);
      }
#pragma unroll
      for (int i = 0; i < 4; ++i)
#pragma unroll
        for (int j2 = 0; j2 < NF; ++j2)
          acc[i][j2] = __builtin_amdgcn_mfma_f32_16x16x32_bf16(
              af[i], bf[j2], acc[i][j2], 0, 0, 0);
    }
    asm volatile("s_waitcnt vmcnt(0)");
    __syncthreads();
  }
#undef GSTAGE

#pragma unroll
  for (int j2 = 0; j2 < NF; ++j2) {
    const int n = n0 + wc * (BN / 2) + j2 * 16 + r15;
    const float bv = bias[n];
#pragma unroll
    for (int i = 0; i < 4; ++i) {
      const int mb = m0 + wr * 64 + i * 16 + g * 4;
      float v[4];
#pragma unroll
      for (int rr = 0; rr < 4; ++rr) v[rr] = acc[i][j2][rr] + bv;
      if (EPI == 1) {
#pragma unroll
        for (int rr = 0; rr < 4; ++rr) fo[(size_t)(mb + rr) * N + n] = v[rr];
      } else {
        const int b = mb >> 11, t = mb & 2047;
        const int sec = n >> 10, nn = n & 1023;
        const int h = nn >> 6, d = nn & 63;
        if (sec == 0) {
          u16* base = o0 + ((size_t)((b * 16 + h) * 2048 + t)) * 64 + d;
#pragma unroll
          for (int rr = 0; rr < 4; ++rr) base[rr * 64] = tobf(v[rr] * SM_SCALE);
        } else if (sec == 1) {
          u16* base = o1 + ((size_t)((b * 16 + h) * 2048 + t)) * 64 + d;
#pragma unroll
          for (int rr = 0; rr < 4; ++rr) base[rr * 64] = tobf(v[rr]);
        } else {
          u32* base = (u32*)(o2 + ((size_t)((b * 16 + h) * 64 + d)) * 2048 + t);
          base[0] = (u32)tobf(v[0]) | ((u32)tobf(v[1]) << 16);
          base[1] = (u32)tobf(v[2]) | ((u32)tobf(v[3]) << 16);
        }
      }
    }
  }
}

// ---------------- piece tables (pid 0..33) --------------------------------
static __device__ const signed char PT_C[34] =
    {15,15,15,15,14,14,14,13,13,13,12,12,12,11,11,11,10,10,10,9,9,8,8,7,7,6,6,5,5,4,3,2,1,0};
static __device__ const signed char PT_K0[34] =
    {0,8,16,24,0,10,20,0,9,18,0,8,17,0,8,16,0,7,14,0,10,0,9,0,8,0,7,0,6,0,0,0,0,0};
static __device__ const signed char PT_KN[34] =
    {8,16,24,32,10,20,30,9,18,28,8,17,26,8,16,24,7,14,22,10,20,9,18,8,16,7,14,6,12,10,8,6,4,2};
static __device__ const signed char PT_SL[34] =
    {-1,0,1,2,-1,3,4,-1,5,6,-1,7,8,-1,9,10,-1,11,12,-1,13,-1,14,-1,15,-1,16,-1,17,-2,-2,-2,-2,-2};

// ---------------- causal flash attention v6 -------------------------------
__global__ __launch_bounds__(256) void attn_kernel(
    const u16* __restrict__ qb, const u16* __restrict__ kb,
    const u16* __restrict__ vt, u16* __restrict__ yb,
    u16* __restrict__ party, float* __restrict__ partM) {
  __shared__ __align__(16) u16 Ks[2][64 * 64];
  __shared__ __align__(16) u16 Vs[2][64 * 64];
  const int tid = threadIdx.x;
  const int lane = tid & 63;
  const int w = tid >> 6;                       // 0..3
  const int q31 = lane & 31, hi = lane >> 5;
  const int bx = blockIdx.x;
  const int pid = bx >> 5, bh = bx & 31;
  const int c = PT_C[pid];
  const int kt0 = PT_K0[pid], ktN = PT_KN[pid];
  const int slot = PT_SL[pid];

  const int q0 = c * 128 + w * 32;              // wave's first q row
  const int qmax = q0 + 31;
  const int qg = q0 + q31;                      // this lane's q row

  const int srow = tid >> 3;                    // 0..31
  const int scolb = ((tid & 7) * 16) ^ ((srow & 7) << 4);
  const u16* ksrc = kb + ((size_t)bh * 2048 + srow) * 64 + (scolb >> 1);
  const u16* vsrc = vt + ((size_t)bh * 64 + srow) * 2048 + (scolb >> 1);

#define STAGE(buf, kt)                                                     \
  do {                                                                     \
    gload_lds16(ksrc + (size_t)(kt) * 4096, (char*)Ks[buf] + w * 1024);    \
    gload_lds16(ksrc + (size_t)(kt) * 4096 + 32 * 64,                      \
                (char*)Ks[buf] + 4096 + w * 1024);                         \
    gload_lds16(vsrc + (kt) * 64, (char*)Vs[buf] + w * 1024);              \
    gload_lds16(vsrc + (kt) * 64 + 32 * 2048,                              \
                (char*)Vs[buf] + 4096 + w * 1024);                         \
  } while (0)

  const u16* qrow = qb + ((size_t)bh * 2048 + qg) * 64;
  bf16x8 aq[4];
#pragma unroll
  for (int ks = 0; ks < 4; ++ks)
    aq[ks] = *(const bf16x8*)(qrow + ks * 16 + 8 * hi);

  f32x16 o0 = {}, o1 = {};      // O^T: lane q=q31; d=(r&3)+8(r>>2)+4hi (+32)
  float m = -INFINITY, l = 0.f; // per-lane (per-q-row) softmax state

  STAGE(0, kt0);
  __syncthreads();
  int cur = 0;
  for (int kt = kt0; kt < ktN; ++kt) {
    if (kt + 1 < ktN) STAGE(cur ^ 1, kt + 1);
    if (kt * 64 <= qmax) {
      const char* Kc = (const char*)Ks[cur];
      const char* Vc = (const char*)Vs[cur];
      const int swz = (q31 & 7) << 4;

      f32x16 s0 = {}, s1 = {};
      __builtin_amdgcn_s_setprio(1);
#pragma unroll
      for (int ks = 0; ks < 4; ++ks) {
        int cb = (32 * ks + 16 * hi) ^ swz;
        bf16x8 k0 = *(const bf16x8*)(Kc + q31 * 128 + cb);
        s0 = __builtin_amdgcn_mfma_f32_32x32x16_bf16(k0, aq[ks], s0, 0, 0, 0);
        bf16x8 k1 = *(const bf16x8*)(Kc + (32 + q31) * 128 + cb);
        s1 = __builtin_amdgcn_mfma_f32_32x32x16_bf16(k1, aq[ks], s1, 0, 0, 0);
      }
      __builtin_amdgcn_s_setprio(0);

      if (kt * 64 + 63 > q0) {
        const int thr = qg - kt * 64;
#pragma unroll
        for (int r = 0; r < 16; ++r) {
          const int off = (r & 3) + 8 * (r >> 2) + 4 * hi;
          if (off > thr) s0[r] = -INFINITY;
          if (off + 32 > thr) s1[r] = -INFINITY;
        }
      }
      f32x16 mx;
#pragma unroll
      for (int r = 0; r < 16; ++r) mx[r] = fmaxf(s0[r], s1[r]);
#pragma unroll
      for (int st = 8; st >= 1; st >>= 1)
#pragma unroll
        for (int r = 0; r < st; ++r) mx[r] = fmaxf(mx[r], mx[r + st]);
      float mt = fmaxf(mx[0], __shfl_xor(mx[0], 32, 64));

      if (kt == kt0) {
        m = mt;
      } else if (__any(mt > m + 8.f)) {
        float mnew = fmaxf(m, mt);
        float alpha = exp2f(m - mnew);
        m = mnew;
        l *= alpha;
#pragma unroll
        for (int r = 0; r < 16; ++r) {
          o0[r] *= alpha;
          o1[r] *= alpha;
        }
      }
#pragma unroll
      for (int r = 0; r < 16; ++r) {
        s0[r] = exp2f(s0[r] - m);
        s1[r] = exp2f(s1[r] - m);
      }
      {
        float la = 0.f, lb = 0.f, lc2 = 0.f, ld = 0.f;
#pragma unroll
        for (int r = 0; r < 16; r += 2) {
          la += s0[r];
          lb += s0[r + 1];
          lc2 += s1[r];
          ld += s1[r + 1];
        }
        l += (la + lb) + (lc2 + ld);
      }
      u32 W[16];
#pragma unroll
      for (int i2 = 0; i2 < 8; ++i2) {
        asm("v_cvt_pk_bf16_f32 %0, %1, %2"
            : "=v"(W[i2]) : "v"(s0[2 * i2]), "v"(s0[2 * i2 + 1]));
        asm("v_cvt_pk_bf16_f32 %0, %1, %2"
            : "=v"(W[8 + i2]) : "v"(s1[2 * i2]), "v"(s1[2 * i2 + 1]));
      }
#pragma unroll
      for (int b4 = 0; b4 < 16; b4 += 4) {
        asm("v_permlane32_swap_b32 %0, %1" : "+v"(W[b4]), "+v"(W[b4 + 2]));
        asm("v_permlane32_swap_b32 %0, %1" : "+v"(W[b4 + 1]), "+v"(W[b4 + 3]));
      }
      __builtin_amdgcn_s_setprio(1);
#pragma unroll
      for (int ks = 0; ks < 4; ++ks) {
        u32x4 pwv = {W[4 * ks], W[4 * ks + 1], W[4 * ks + 2], W[4 * ks + 3]};
        bf16x8 pf = __builtin_bit_cast(bf16x8, pwv);
        int cb = (32 * ks + 16 * hi) ^ swz;
        bf16x8 v0 = *(const bf16x8*)(Vc + q31 * 128 + cb);
        o0 = __builtin_amdgcn_mfma_f32_32x32x16_bf16(v0, pf, o0, 0, 0, 0);
        bf16x8 v1 = *(const bf16x8*)(Vc + (32 + q31) * 128 + cb);
        o1 = __builtin_amdgcn_mfma_f32_32x32x16_bf16(v1, pf, o1, 0, 0, 0);
      }
      __builtin_amdgcn_s_setprio(0);
    }
    __syncthreads();
    cur ^= 1;
  }
#undef STAGE

  l += __shfl_xor(l, 32, 64);
  float inv = 1.0f / l;

  u32* dst;
  if (slot >= 0) {
    dst = (u32*)(party +
                 ((size_t)((slot * 32 + bh) * 128 + w * 32 + q31)) * 64);
  } else {
    int b = bh >> 4, hd = bh & 15;
    dst = (u32*)(yb + ((size_t)b * 2048 + qg) * 1024 + hd * 64);
  }
#pragma unroll
  for (int r = 0; r < 16; r += 2) {
    int d = (r & 3) + 8 * (r >> 2) + 4 * hi;
    dst[d >> 1] = (u32)tobf(o0[r] * inv) | ((u32)tobf(o0[r + 1] * inv) << 16);
    dst[(d + 32) >> 1] =
        (u32)tobf(o1[r] * inv) | ((u32)tobf(o1[r + 1] * inv) << 16);
  }
  if (slot != -2 && hi == 0)
    partM[(pid * 32 + bh) * 128 + w * 32 + q31] = m + log2f(l);
}

// ---------------- combine split partials ----------------------------------
static __device__ const signed char CB_PID[11] = {0,4,7,10,13,16,19,21,23,25,27};
static __device__ const signed char CB_P[11]   = {4,3,3,3,3,3,2,2,2,2,2};
static __device__ const signed char CB_SL[11]  = {0,3,5,7,9,11,13,14,15,16,17};

__global__ __launch_bounds__(256) void attn_combine(
    const u16* __restrict__ party, const float* __restrict__ partM,
    u16* __restrict__ yb) {
  const int gi = blockIdx.x;                  // 0..351
  const int ci = gi >> 5, bh = gi & 31;
  const int c = 15 - ci;
  const int pidb = CB_PID[ci], P = CB_P[ci], slb = CB_SL[ci];
  const int row = threadIdx.x >> 1, off = (threadIdx.x & 1) * 32;

  const float M0 = partM[((pidb + 0) * 32 + bh) * 128 + row];
  const float M1 = partM[((pidb + 1) * 32 + bh) * 128 + row];
  const float M2 = (P > 2) ? partM[((pidb + 2) * 32 + bh) * 128 + row] : -INFINITY;
  const float M3 = (P > 3) ? partM[((pidb + 3) * 32 + bh) * 128 + row] : -INFINITY;
  const float Mm = fmaxf(fmaxf(M0, M1), fmaxf(M2, M3));
  const float w0 = exp2f(M0 - Mm), w1 = exp2f(M1 - Mm);
  const float w2 = exp2f(M2 - Mm), w3 = exp2f(M3 - Mm);
  const float inv = 1.f / (w0 + w1 + w2 + w3);

  const int b = bh >> 4, head = bh & 15, t = c * 128 + row;
  u16* y = yb + ((size_t)b * 2048 + t) * 1024 + head * 64 + off;

  float acc[32];
#pragma unroll
  for (int j = 0; j < 4; ++j) {
    u16x8 a = *(const u16x8*)(y + j * 8);
#pragma unroll
    for (int e = 0; e < 8; ++e) acc[j * 8 + e] = frombf(a[e]) * w0;
  }
  {
    const u16* p1 = party + ((size_t)((slb + 0) * 32 + bh) * 128 + row) * 64 + off;
#pragma unroll
    for (int j = 0; j < 4; ++j) {
      u16x8 a = *(const u16x8*)(p1 + j * 8);
#pragma unroll
      for (int e = 0; e < 8; ++e) acc[j * 8 + e] += frombf(a[e]) * w1;
    }
  }
  if (P > 2) {
    const u16* p2 = party + ((size_t)((slb + 1) * 32 + bh) * 128 + row) * 64 + off;
#pragma unroll
    for (int j = 0; j < 4; ++j) {
      u16x8 a = *(const u16x8*)(p2 + j * 8);
#pragma unroll
      for (int e = 0; e < 8; ++e) acc[j * 8 + e] += frombf(a[e]) * w2;
    }
  }
  if (P > 3) {
    const u16* p3 = party + ((size_t)((slb + 2) * 32 + bh) * 128 + row) * 64 + off;
#pragma unroll
    for (int j = 0; j < 4; ++j) {
      u16x8 a = *(const u16x8*)(p3 + j * 8);
#pragma unroll
      for (int e = 0; e < 8; ++e) acc[j * 8 + e] += frombf(a[e]) * w3;
    }
  }
#pragma unroll
  for (int j = 0; j < 4; ++j) {
    u16x8 ov;
#pragma unroll
    for (int e = 0; e < 8; ++e) ov[e] = tobf(acc[j * 8 + e] * inv);
    *(u16x8*)(y + j * 8) = ov;
  }
}

extern "C" void kernel_launch(void* const* d_in, const int* in_sizes, int n_in,
                              void* d_out, int out_size, void* d_ws,
                              size_t ws_size, hipStream_t stream) {
  const float* x = (const float*)d_in[0];
  const float* w_attn = (const float*)d_in[1];
  const float* b_attn = (const float*)d_in[2];
  const float* w_proj = (const float*)d_in[3];
  const float* b_proj = (const float*)d_in[4];
  float* out = (float*)d_out;
  char* ws = (char*)d_ws;

  u16* xb = (u16*)ws;                          // 8 MB [4096][1024] (dead after GEMM1)
  u16* wat = (u16*)(ws + (8ull << 20));        // 6 MB (dead after GEMM1)
  u16* wpt = (u16*)(ws + (14ull << 20));       // 2 MB (alive until GEMM2)
  u16* qbuf = (u16*)(ws + (16ull << 20));      // 8 MB [B,H,T,D] (q pre-scaled)
  u16* kbuf = (u16*)(ws + (24ull << 20));      // 8 MB [B,H,T,D]
  u16* vtb = (u16*)(ws + (32ull << 20));       // 8 MB [B,H,D,T]
  u16* yb = (u16*)(ws + (40ull << 20));        // 8 MB [4096][1024]
  // partials reuse dead xb/wat region [0,14 MB):
  u16* party = (u16*)ws;                       // 9.0 MB: 576 slots [128][64] bf16
  float* partM = (float*)(ws + (10ull << 20)); // 0.56 MB: [34*32][128] f32

  convert_f32_bf16<<<2048, 256, 0, stream>>>(x, xb, (4096 * 1024) / 8);
  transpose_w<<<3072, 256, 0, stream>>>(w_attn, wat, 1024, 3072);
  transpose_w<<<1024, 256, 0, stream>>>(w_proj, wpt, 1024, 1024);
  gemm_bt<0, 192><<<32 * 16, 256, 0, stream>>>(xb, wat, b_attn, qbuf, kbuf,
                                               vtb, nullptr, 4096, 3072, 1024);
  attn_kernel<<<34 * 32, 256, 0, stream>>>(qbuf, kbuf, vtb, yb, party, partM);
  attn_combine<<<352, 256, 0, stream>>>(party, partM, yb);
  gemm_bt<1, 64><<<32 * 16, 256, 0, stream>>>(yb, wpt, b_proj, nullptr,
                                              nullptr, nullptr, out, 4096,
                                              1024, 1024);
}

// Round 8
// 118.141 us; speedup vs baseline: 1.4292x; 1.0406x over previous
//
#include <hip/hip_runtime.h>
#include <hip/hip_bf16.h>

typedef __bf16 bf16x8 __attribute__((ext_vector_type(8)));
typedef float f32x4 __attribute__((ext_vector_type(4)));
typedef float f32x16 __attribute__((ext_vector_type(16)));
typedef unsigned short u16;
typedef unsigned int u32;
typedef u16 u16x8 __attribute__((ext_vector_type(8)));
typedef u32 u32x4 __attribute__((ext_vector_type(4)));

#define SM_SCALE 0.1803368801111244f  // (1/8) * log2(e), folded into Q

// f32 -> bf16 round-to-nearest-even
__device__ inline u16 tobf(float f) {
  u32 u = __builtin_bit_cast(u32, f);
  u32 r = (u + 0x7fffu + ((u >> 16) & 1u)) >> 16;
  return (u16)r;
}

__device__ inline float frombf(u16 h) {
  return __builtin_bit_cast(float, (u32)h << 16);
}

__device__ inline void gload_lds16(const void* g, void* lds) {
  __builtin_amdgcn_global_load_lds(
      (const __attribute__((address_space(1))) u32*)g,
      (__attribute__((address_space(3))) u32*)lds, 16, 0, 0);
}

// ---------------- convert x (f32 -> bf16), 8 elems/thread ----------------
__global__ void convert_f32_bf16(const float* __restrict__ in,
                                 u16* __restrict__ out, int n8) {
  int i = blockIdx.x * blockDim.x + threadIdx.x;
  int stride = gridDim.x * blockDim.x;
  for (; i < n8; i += stride) {
    const float4* p = (const float4*)in + (size_t)i * 2;
    float4 a = p[0], b = p[1];
    u16x8 v;
    v[0] = tobf(a.x); v[1] = tobf(a.y); v[2] = tobf(a.z); v[3] = tobf(a.w);
    v[4] = tobf(b.x); v[5] = tobf(b.y); v[6] = tobf(b.z); v[7] = tobf(b.w);
    *(u16x8*)(out + (size_t)i * 8) = v;
  }
}

// ---------------- transpose + cast weights: out[n][k] = in[k][n] ----------
__global__ void transpose_w(const float* __restrict__ in,
                            u16* __restrict__ out, int K, int N) {
  __shared__ float tile[32][33];
  int nbx = N >> 5;
  int bx = blockIdx.x % nbx, by = blockIdx.x / nbx;
  int k0 = by << 5, n0 = bx << 5;
  int tx = threadIdx.x & 31, ty = threadIdx.x >> 5;
#pragma unroll
  for (int j = 0; j < 4; ++j) {
    int row = ty + j * 8;
    tile[row][tx] = in[(size_t)(k0 + row) * N + n0 + tx];
  }
  __syncthreads();
#pragma unroll
  for (int j = 0; j < 4; ++j) {
    int row = ty + j * 8;
    out[(size_t)(n0 + row) * K + k0 + tx] = tobf(tile[tx][row]);
  }
}

// ---------------- GEMM: C[M,N] = A[M,K] * Bt[N,K]^T  (bf16 in, f32 acc) ---
// BM=128, BN in {192, 64}. 2-phase double-buffered staging; XCD swizzle.
// EPI 0: q (scaled) -> [bh][t][64]; k -> kpack; v -> vpack. EPI 1: f32+bias.
// kpack: [bh][kt][ks][h2][hi][q31][e]  (frag-linear for swapped-QK A-operand)
// vpack: [bh][kt][ks][d2][hi][d31][e]  (frag-linear for PV A-operand)
template <int EPI, int BN>
__global__ __launch_bounds__(256) void gemm_bt(
    const u16* __restrict__ A, const u16* __restrict__ Bt,
    const float* __restrict__ bias,
    u16* __restrict__ o0, u16* __restrict__ o1, u16* __restrict__ o2,
    float* __restrict__ fo, int M, int N, int K) {
  constexpr int NF = BN / 32;
  __shared__ __align__(16) u16 As[2][128 * 64];
  __shared__ __align__(16) u16 Bs[2][BN * 64];
  const int tid = threadIdx.x;
  const int lane = tid & 63;
  const int wave = tid >> 6;
  const int nbn = N / BN;
  int bid = (int)blockIdx.x;
  const int cpx = (int)gridDim.x >> 3;
  bid = (bid & 7) * cpx + (bid >> 3);
  const int bm = bid / nbn, bn = bid % nbn;
  const int m0 = bm << 7, n0 = bn * BN;
  const int wr = wave >> 1, wc = wave & 1;
  const int r15 = lane & 15, g = lane >> 4;

  f32x4 acc[4][NF] = {};

#define GSTAGE(buf, kt)                                                    \
  do {                                                                     \
    _Pragma("unroll")                                                      \
    for (int j = 0; j < 4; ++j) {                                          \
      int c = j * 4 + wave;                                                \
      int byte0 = c * 1024 + lane * 16;                                    \
      int row = byte0 >> 7;                                                \
      int colb = (byte0 & 127) ^ ((row & 7) << 4);                         \
      gload_lds16(A + (size_t)(m0 + row) * K + (kt) * 64 + (colb >> 1),    \
                  (char*)As[(buf)] + c * 1024);                            \
    }                                                                      \
    _Pragma("unroll")                                                      \
    for (int j = 0; j < NF; ++j) {                                         \
      int c = j * 4 + wave;                                                \
      int byte0 = c * 1024 + lane * 16;                                    \
      int row = byte0 >> 7;                                                \
      int colb = (byte0 & 127) ^ ((row & 7) << 4);                         \
      gload_lds16(Bt + (size_t)(n0 + row) * K + (kt) * 64 + (colb >> 1),   \
                  (char*)Bs[(buf)] + c * 1024);                            \
    }                                                                      \
  } while (0)

  const int nkt = K >> 6;
  GSTAGE(0, 0);
  asm volatile("s_waitcnt vmcnt(0)");
  __syncthreads();
  for (int kt = 0; kt < nkt; ++kt) {
    const int cur = kt & 1;
    if (kt + 1 < nkt) GSTAGE(cur ^ 1, kt + 1);
#pragma unroll
    for (int kk = 0; kk < 2; ++kk) {
      bf16x8 af[4], bf[NF];
#pragma unroll
      for (int i = 0; i < 4; ++i) {
        int rowA = wr * 64 + i * 16 + r15;
        int ca = (kk * 64 + 16 * g) ^ ((rowA & 7) << 4);
        af[i] = *(const bf16x8*)((const char*)As[cur] + rowA * 128 + ca);
      }
#pragma unroll
      for (int j2 = 0; j2 < NF; ++j2) {
        int rowB = wc * (BN / 2) + j2 * 16 + r15;
        int cb = (kk * 64 + 16 * g) ^ ((rowB & 7) << 4);
        bf[j2] = *(const bf16x8*)((const char*)Bs[cur] + rowB * 128 + cb);
      }
#pragma unroll
      for (int i = 0; i < 4; ++i)
#pragma unroll
        for (int j2 = 0; j2 < NF; ++j2)
          acc[i][j2] = __builtin_amdgcn_mfma_f32_16x16x32_bf16(
              af[i], bf[j2], acc[i][j2], 0, 0, 0);
    }
    asm volatile("s_waitcnt vmcnt(0)");
    __syncthreads();
  }
#undef GSTAGE

#pragma unroll
  for (int j2 = 0; j2 < NF; ++j2) {
    const int n = n0 + wc * (BN / 2) + j2 * 16 + r15;
    const float bv = bias[n];
#pragma unroll
    for (int i = 0; i < 4; ++i) {
      const int mb = m0 + wr * 64 + i * 16 + g * 4;
      float v[4];
#pragma unroll
      for (int rr = 0; rr < 4; ++rr) v[rr] = acc[i][j2][rr] + bv;
      if (EPI == 1) {
#pragma unroll
        for (int rr = 0; rr < 4; ++rr) fo[(size_t)(mb + rr) * N + n] = v[rr];
      } else {
        const int b = mb >> 11, t = mb & 2047;
        const int sec = n >> 10, nn = n & 1023;
        const int h = nn >> 6, d = nn & 63;
        const int bh = b * 16 + h;
        if (sec == 0) {
          u16* base = o0 + ((size_t)bh * 2048 + t) * 64 + d;
#pragma unroll
          for (int rr = 0; rr < 4; ++rr) base[rr * 64] = tobf(v[rr] * SM_SCALE);
        } else if (sec == 1) {
          // kpack[bh][kt][ks=d>>4][h2][hi=(d>>3)&1][q31][e=d&7]
          u16* kb = o1 +
                    (((size_t)(bh * 32 + (t >> 6)) * 4 + (d >> 4)) * 2) * 512 +
                    ((d >> 3) & 1) * 256 + (d & 7);
          const int tb = t & 63;
#pragma unroll
          for (int rr = 0; rr < 4; ++rr) {
            int r = tb + rr;
            kb[(r >> 5) * 512 + (r & 31) * 8] = tobf(v[rr]);
          }
        } else {
          // vpack[bh][kt][ks=(t&63)>>4][d2=d>>5][hi][d31][e=t&7], 4 consec t
          const int tl = t & 63;
          u16* vb = o2 +
                    ((((size_t)(bh * 32 + (t >> 6)) * 4 + (tl >> 4)) * 2 +
                      (d >> 5)) * 512) +
                    ((tl >> 3) & 1) * 256 + (d & 31) * 8 + (tl & 7);
          u32* p = (u32*)vb;
          p[0] = (u32)tobf(v[0]) | ((u32)tobf(v[1]) << 16);
          p[1] = (u32)tobf(v[2]) | ((u32)tobf(v[3]) << 16);
        }
      }
    }
  }
}

// ---------------- piece tables (pid 0..33) --------------------------------
static __device__ const signed char PT_C[34] =
    {15,15,15,15,14,14,14,13,13,13,12,12,12,11,11,11,10,10,10,9,9,8,8,7,7,6,6,5,5,4,3,2,1,0};
static __device__ const signed char PT_K0[34] =
    {0,8,16,24,0,10,20,0,9,18,0,8,17,0,8,16,0,7,14,0,10,0,9,0,8,0,7,0,6,0,0,0,0,0};
static __device__ const signed char PT_KN[34] =
    {8,16,24,32,10,20,30,9,18,28,8,17,26,8,16,24,7,14,22,10,20,9,18,8,16,7,14,6,12,10,8,6,4,2};
static __device__ const signed char PT_SL[34] =
    {-1,0,1,2,-1,3,4,-1,5,6,-1,7,8,-1,9,10,-1,11,12,-1,13,-1,14,-1,15,-1,16,-1,17,-2,-2,-2,-2,-2};

// ---------------- causal flash attention v7: barrier-free, L2-direct ------
// 256 thr / 4 independent waves (no LDS, no __syncthreads). Wave owns 32 q
// rows; K/V read straight from frag-packed global (L1/L2-resident; blocks of
// a bh land on one XCD since bid%8==bh%8). Swapped mfma(K,Q) softmax.
__global__ __launch_bounds__(256) void attn_kernel(
    const u16* __restrict__ qb, const u16* __restrict__ kpk,
    const u16* __restrict__ vpk, u16* __restrict__ yb,
    u16* __restrict__ party, float* __restrict__ partM) {
  const int tid = threadIdx.x;
  const int lane = tid & 63;
  const int w = tid >> 6;                       // 0..3
  const int q31 = lane & 31, hi = lane >> 5;
  const int bx = blockIdx.x;
  const int pid = bx >> 5, bh = bx & 31;
  const int c = PT_C[pid];
  const int kt0 = PT_K0[pid], ktN = PT_KN[pid];
  const int slot = PT_SL[pid];

  const int q0 = c * 128 + w * 32;              // wave's first q row
  const int qg = q0 + q31;                      // this lane's q row
  const int qmax = q0 + 31;
  const int ktEnd = min(ktN, (qmax >> 6) + 1);  // per-wave early exit

  // Q fragments: lane holds Q[qg][d = ks*16 + 8*hi .. +8), ks=0..3
  const u16* qrow = qb + ((size_t)bh * 2048 + qg) * 64;
  bf16x8 aq[4];
#pragma unroll
  for (int ks = 0; ks < 4; ++ks)
    aq[ks] = *(const bf16x8*)(qrow + ks * 16 + 8 * hi);

  f32x16 o0 = {}, o1 = {};      // O^T: lane q=q31; d=(r&3)+8(r>>2)+4hi (+32)
  float m = -INFINITY, l = 0.f; // per-lane (per-q-row) softmax state

  // frag-pack bases: per (bh,kt) block = 4096 u16 (8 frags x 512)
  const u16* kbh = kpk + (size_t)bh * 32 * 4096 + lane * 8;
  const u16* vbh = vpk + (size_t)bh * 32 * 4096 + lane * 8;

  for (int kt = kt0; kt < ktEnd; ++kt) {
    const u16* kp = kbh + (size_t)kt * 4096;
    const u16* vp = vbh + (size_t)kt * 4096;

    // K frags: (ks,h2) at kp + (ks*2+h2)*512 — lane-linear 1KB loads
    bf16x8 kf[8];
#pragma unroll
    for (int j = 0; j < 8; ++j) kf[j] = *(const bf16x8*)(kp + j * 512);

    f32x16 s0 = {}, s1 = {};
    __builtin_amdgcn_s_setprio(1);
#pragma unroll
    for (int ks = 0; ks < 4; ++ks) {
      s0 = __builtin_amdgcn_mfma_f32_32x32x16_bf16(kf[2 * ks], aq[ks], s0, 0, 0, 0);
      s1 = __builtin_amdgcn_mfma_f32_32x32x16_bf16(kf[2 * ks + 1], aq[ks], s1, 0, 0, 0);
    }
    __builtin_amdgcn_s_setprio(0);

    // causal mask (diagonal tiles only; wave-uniform branch)
    if (kt * 64 + 63 > q0) {
      const int thr = qg - kt * 64;
#pragma unroll
      for (int r = 0; r < 16; ++r) {
        const int off = (r & 3) + 8 * (r >> 2) + 4 * hi;
        if (off > thr) s0[r] = -INFINITY;
        if (off + 32 > thr) s1[r] = -INFINITY;
      }
    }
    // tree max over 32 in-lane values
    f32x16 mx;
#pragma unroll
    for (int r = 0; r < 16; ++r) mx[r] = fmaxf(s0[r], s1[r]);
#pragma unroll
    for (int st = 8; st >= 1; st >>= 1)
#pragma unroll
      for (int r = 0; r < st; ++r) mx[r] = fmaxf(mx[r], mx[r + st]);
    float mt = fmaxf(mx[0], __shfl_xor(mx[0], 32, 64));

    if (kt == kt0) {
      m = mt;
    } else if (__any(mt > m + 8.f)) {
      float mnew = fmaxf(m, mt);
      float alpha = exp2f(m - mnew);
      m = mnew;
      l *= alpha;
#pragma unroll
      for (int r = 0; r < 16; ++r) {
        o0[r] *= alpha;
        o1[r] *= alpha;
      }
    }
#pragma unroll
    for (int r = 0; r < 16; ++r) {
      s0[r] = exp2f(s0[r] - m);
      s1[r] = exp2f(s1[r] - m);
    }
    {
      float la = 0.f, lb = 0.f, lc2 = 0.f, ld = 0.f;
#pragma unroll
      for (int r = 0; r < 16; r += 2) {
        la += s0[r];
        lb += s0[r + 1];
        lc2 += s1[r];
        ld += s1[r + 1];
      }
      l += (la + lb) + (lc2 + ld);
    }
    // pack to bf16 pairs then redistribute halves across lane<32/>=32
    u32 W[16];
#pragma unroll
    for (int i2 = 0; i2 < 8; ++i2) {
      asm("v_cvt_pk_bf16_f32 %0, %1, %2"
          : "=v"(W[i2]) : "v"(s0[2 * i2]), "v"(s0[2 * i2 + 1]));
      asm("v_cvt_pk_bf16_f32 %0, %1, %2"
          : "=v"(W[8 + i2]) : "v"(s1[2 * i2]), "v"(s1[2 * i2 + 1]));
    }
#pragma unroll
    for (int b4 = 0; b4 < 16; b4 += 4) {
      asm("v_permlane32_swap_b32 %0, %1" : "+v"(W[b4]), "+v"(W[b4 + 2]));
      asm("v_permlane32_swap_b32 %0, %1" : "+v"(W[b4 + 1]), "+v"(W[b4 + 3]));
    }
    // V frags: (ks,d2) at vp + (ks*2+d2)*512
    bf16x8 vf[8];
#pragma unroll
    for (int j = 0; j < 8; ++j) vf[j] = *(const bf16x8*)(vp + j * 512);

    // PV: O^T += V^T * P^T
    __builtin_amdgcn_s_setprio(1);
#pragma unroll
    for (int ks = 0; ks < 4; ++ks) {
      u32x4 pwv = {W[4 * ks], W[4 * ks + 1], W[4 * ks + 2], W[4 * ks + 3]};
      bf16x8 pf = __builtin_bit_cast(bf16x8, pwv);
      o0 = __builtin_amdgcn_mfma_f32_32x32x16_bf16(vf[2 * ks], pf, o0, 0, 0, 0);
      o1 = __builtin_amdgcn_mfma_f32_32x32x16_bf16(vf[2 * ks + 1], pf, o1, 0, 0, 0);
    }
    __builtin_amdgcn_s_setprio(0);
  }

  // final: combine partner's partial sum (other kv half, same q)
  l += __shfl_xor(l, 32, 64);
  float inv = 1.0f / l;

  u32* dst;
  if (slot >= 0) {
    dst = (u32*)(party +
                 ((size_t)((slot * 32 + bh) * 128 + w * 32 + q31)) * 64);
  } else {
    int b = bh >> 4, hd = bh & 15;
    dst = (u32*)(yb + ((size_t)b * 2048 + qg) * 1024 + hd * 64);
  }
#pragma unroll
  for (int r = 0; r < 16; r += 2) {
    int d = (r & 3) + 8 * (r >> 2) + 4 * hi;
    dst[d >> 1] = (u32)tobf(o0[r] * inv) | ((u32)tobf(o0[r + 1] * inv) << 16);
    dst[(d + 32) >> 1] =
        (u32)tobf(o1[r] * inv) | ((u32)tobf(o1[r + 1] * inv) << 16);
  }
  if (slot != -2 && hi == 0)
    partM[(pid * 32 + bh) * 128 + w * 32 + q31] = m + log2f(l);
}

// ---------------- combine split partials ----------------------------------
static __device__ const signed char CB_PID[11] = {0,4,7,10,13,16,19,21,23,25,27};
static __device__ const signed char CB_P[11]   = {4,3,3,3,3,3,2,2,2,2,2};
static __device__ const signed char CB_SL[11]  = {0,3,5,7,9,11,13,14,15,16,17};

__global__ __launch_bounds__(256) void attn_combine(
    const u16* __restrict__ party, const float* __restrict__ partM,
    u16* __restrict__ yb) {
  const int gi = blockIdx.x;                  // 0..351
  const int ci = gi >> 5, bh = gi & 31;
  const int c = 15 - ci;
  const int pidb = CB_PID[ci], P = CB_P[ci], slb = CB_SL[ci];
  const int row = threadIdx.x >> 1, off = (threadIdx.x & 1) * 32;

  const float M0 = partM[((pidb + 0) * 32 + bh) * 128 + row];
  const float M1 = partM[((pidb + 1) * 32 + bh) * 128 + row];
  const float M2 = (P > 2) ? partM[((pidb + 2) * 32 + bh) * 128 + row] : -INFINITY;
  const float M3 = (P > 3) ? partM[((pidb + 3) * 32 + bh) * 128 + row] : -INFINITY;
  const float Mm = fmaxf(fmaxf(M0, M1), fmaxf(M2, M3));
  const float w0 = exp2f(M0 - Mm), w1 = exp2f(M1 - Mm);
  const float w2 = exp2f(M2 - Mm), w3 = exp2f(M3 - Mm);
  const float inv = 1.f / (w0 + w1 + w2 + w3);

  const int b = bh >> 4, head = bh & 15, t = c * 128 + row;
  u16* y = yb + ((size_t)b * 2048 + t) * 1024 + head * 64 + off;

  float acc[32];
#pragma unroll
  for (int j = 0; j < 4; ++j) {
    u16x8 a = *(const u16x8*)(y + j * 8);
#pragma unroll
    for (int e = 0; e < 8; ++e) acc[j * 8 + e] = frombf(a[e]) * w0;
  }
  {
    const u16* p1 = party + ((size_t)((slb + 0) * 32 + bh) * 128 + row) * 64 + off;
#pragma unroll
    for (int j = 0; j < 4; ++j) {
      u16x8 a = *(const u16x8*)(p1 + j * 8);
#pragma unroll
      for (int e = 0; e < 8; ++e) acc[j * 8 + e] += frombf(a[e]) * w1;
    }
  }
  if (P > 2) {
    const u16* p2 = party + ((size_t)((slb + 1) * 32 + bh) * 128 + row) * 64 + off;
#pragma unroll
    for (int j = 0; j < 4; ++j) {
      u16x8 a = *(const u16x8*)(p2 + j * 8);
#pragma unroll
      for (int e = 0; e < 8; ++e) acc[j * 8 + e] += frombf(a[e]) * w2;
    }
  }
  if (P > 3) {
    const u16* p3 = party + ((size_t)((slb + 2) * 32 + bh) * 128 + row) * 64 + off;
#pragma unroll
    for (int j = 0; j < 4; ++j) {
      u16x8 a = *(const u16x8*)(p3 + j * 8);
#pragma unroll
      for (int e = 0; e < 8; ++e) acc[j * 8 + e] += frombf(a[e]) * w3;
    }
  }
#pragma unroll
  for (int j = 0; j < 4; ++j) {
    u16x8 ov;
#pragma unroll
    for (int e = 0; e < 8; ++e) ov[e] = tobf(acc[j * 8 + e] * inv);
    *(u16x8*)(y + j * 8) = ov;
  }
}

extern "C" void kernel_launch(void* const* d_in, const int* in_sizes, int n_in,
                              void* d_out, int out_size, void* d_ws,
                              size_t ws_size, hipStream_t stream) {
  const float* x = (const float*)d_in[0];
  const float* w_attn = (const float*)d_in[1];
  const float* b_attn = (const float*)d_in[2];
  const float* w_proj = (const float*)d_in[3];
  const float* b_proj = (const float*)d_in[4];
  float* out = (float*)d_out;
  char* ws = (char*)d_ws;

  u16* xb = (u16*)ws;                          // 8 MB [4096][1024] (dead after GEMM1)
  u16* wat = (u16*)(ws + (8ull << 20));        // 6 MB (dead after GEMM1)
  u16* wpt = (u16*)(ws + (14ull << 20));       // 2 MB (alive until GEMM2)
  u16* qbuf = (u16*)(ws + (16ull << 20));      // 8 MB [bh][t][64] (q pre-scaled)
  u16* kpk = (u16*)(ws + (24ull << 20));       // 8 MB frag-packed K
  u16* vpk = (u16*)(ws + (32ull << 20));       // 8 MB frag-packed V
  u16* yb = (u16*)(ws + (40ull << 20));        // 8 MB [4096][1024]
  // partials reuse dead xb/wat region [0,14 MB):
  u16* party = (u16*)ws;                       // 9.0 MB: 576 slots [128][64] bf16
  float* partM = (float*)(ws + (10ull << 20)); // 0.56 MB: [34*32][128] f32

  convert_f32_bf16<<<2048, 256, 0, stream>>>(x, xb, (4096 * 1024) / 8);
  transpose_w<<<3072, 256, 0, stream>>>(w_attn, wat, 1024, 3072);
  transpose_w<<<1024, 256, 0, stream>>>(w_proj, wpt, 1024, 1024);
  gemm_bt<0, 192><<<32 * 16, 256, 0, stream>>>(xb, wat, b_attn, qbuf, kpk,
                                               vpk, nullptr, 4096, 3072, 1024);
  attn_kernel<<<34 * 32, 256, 0, stream>>>(qbuf, kpk, vpk, yb, party, partM);
  attn_combine<<<352, 256, 0, stream>>>(party, partM, yb);
  gemm_bt<1, 64><<<32 * 16, 256, 0, stream>>>(yb, wpt, b_proj, nullptr,
                                              nullptr, nullptr, out, 4096,
                                              1024, 1024);
}